// Round 17
// baseline (386.604 us; speedup 1.0000x reference)
//
#include <hip/hip_runtime.h>
#include <hip/hip_bf16.h>
#include <math.h>

static constexpr int BN   = 16384;
static constexpr int NFFT = 512;
static constexpr int NBIN = 257;
static constexpr int NH   = 128;
static constexpr int NE   = 256;
static constexpr float EPSF  = 1.1920929e-07f;
static constexpr float LNEPS = 1e-07f;

using short8  = __attribute__((ext_vector_type(8))) short;
using float4v = __attribute__((ext_vector_type(4))) float;

__device__ __forceinline__ float sigm(float x){ return 1.0f/(1.0f+expf(-x)); }
__device__ __forceinline__ ushort f2b(float v){
  __hip_bfloat16 b = __float2bfloat16(v);
  return *reinterpret_cast<ushort*>(&b);
}
__device__ __forceinline__ float b2f(ushort u){
  __hip_bfloat16 b = *reinterpret_cast<__hip_bfloat16*>(&u);
  return __bfloat162float(b);
}

// ---- packed staging-ready layout ----
// matrix [rows][K] stored as chunks: chunk kt (32 k) x row -> 128B:
// 8 slots x 16B; slot p at row r holds LOGICAL slot p^(r&7);
// logical slots 0..3 = hi bf16 of k sub-chunks, 4..7 = lo bf16.
__device__ __forceinline__ size_t pkoff(int rows, int row, int k, int lo){
  const int ls = ((((k >> 3) & 3) | (lo << 2)) ^ (row & 7));
  return (size_t)(k >> 5) * ((size_t)rows << 6) + ((size_t)row << 6) + (ls << 3) + (k & 7);
}
__device__ __forceinline__ void split_pk(float v, ushort* base, int rows, int row, int k){
  ushort h = f2b(v);
  base[pkoff(rows, row, k, 0)] = h;
  base[pkoff(rows, row, k, 1)] = f2b(v - b2f(h));
}
__device__ __forceinline__ float read_pk(const ushort* base, int rows, int row, int k){
  return b2f(base[pkoff(rows, row, k, 0)]) + b2f(base[pkoff(rows, row, k, 1)]);
}

__device__ __forceinline__ void gload16(const ushort* g, ushort* l){
  __builtin_amdgcn_global_load_lds(
      (const __attribute__((address_space(1))) unsigned int*)g,
      (__attribute__((address_space(3))) unsigned int*)l,
      16, 0, 0);
}

// epilogue modes
enum { M_F32 = 0, M_PLANES = 1, M_LSTM = 2, M_EST = 3, M_DEC = 4, M_RFFT = 5 };

// ====== MFMA bf16x2 NT GEMM — A-STATIONARY: block = 32 rows x full N ======
// C[row][col] = sum_k A[row][k]*B[col][k] (+ optional phase2 A2/B2)
// WAVES = N/64 waves; wave wv owns cols wv*64..+64 with acc[2][4].
// Per k-iter: A (4KB) staged ONCE per row-block (vs once per col-block
// before => A-traffic / (N/128)); B (N x 128B) staged whole, L2-resident.
// LDS = 4KB A + N*128B B. Grid = BN/32 row-blocks only.
// MODE_LSTM expects gate-PERMUTED weights/bias: col' = 128*(u>>5)+32*g+(u&31);
// full-N block holds all 4 gate groups => LSTM epilogue fully in-block.
// M_LSTM: aux0 = ORIGINAL state buffer (h,c interleaved); c = aux0[2*idx+1].
template<int MODE, int WAVES>
__global__ __launch_bounds__(WAVES * 64)
void mfma_gemm(const ushort* __restrict__ Apk, int MA, int nkA,
               const ushort* __restrict__ Bpk, int MB,
               const ushort* __restrict__ A2pk, int nkA2,
               const ushort* __restrict__ B2pk, int MB2,
               const float* __restrict__ bias,
               float* __restrict__ C, int ldc,
               const float* __restrict__ aux0,   // LSTM: st base | EST: RI | DEC: ENC
               const ushort* __restrict__ auxpk, // EST: mag packed
               float* __restrict__ out0,         // LSTM: out_state (h,c pairs)
               ushort* __restrict__ opk)         // packed output
{
  constexpr int NT   = WAVES * 64;
  constexpr int LDSU = 2048 + WAVES * 64 * 64;   // ushorts: A[32][64] + B[N][64]
  __shared__ ushort smem[LDSU];
  const int tid  = threadIdx.x;
  const int row0 = blockIdx.x * 32;
  const int lane = tid & 63;
  const int wv   = tid >> 6;
  const int wc   = wv * 64;
  const int fr   = lane & 15;
  const int quad = lane >> 4;

  float4v acc[2][4];
  #pragma unroll
  for (int i = 0; i < 2; ++i)
    #pragma unroll
    for (int j = 0; j < 4; ++j)
      acc[i][j] = float4v{0.f, 0.f, 0.f, 0.f};

  const int nt0 = nkA;
  const int nt1 = A2pk ? nkA2 : 0;
  const int nt  = nt0 + nt1;

  const size_t astr  = (size_t)MA << 6;
  const size_t bstr  = (size_t)MB << 6;
  const size_t bstr2 = (size_t)MB2 << 6;
  constexpr int NSEG = 4 + WAVES * 8;            // A segs + B segs (8 rows each)

  #pragma unroll 1
  for (int t = 0; t < nt; ++t) {
    const ushort* Ap = (t < nt0) ? (Apk + (size_t)t * astr)
                                 : (A2pk + (size_t)(t - nt0) * astr);
    const ushort* Bp = (t < nt0) ? (Bpk + (size_t)t * bstr)
                                 : (B2pk + (size_t)(t - nt0) * bstr2);
    #pragma unroll 1
    for (int s = wv; s < NSEG; s += WAVES) {
      if (s < 4)
        gload16(Ap + ((size_t)(row0 + s * 8) << 6) + lane * 8, &smem[s * 512]);
      else
        gload16(Bp + ((size_t)((s - 4) * 8) << 6) + lane * 8,
                &smem[2048 + (s - 4) * 512]);
    }
    asm volatile("s_waitcnt vmcnt(0)" ::: "memory");
    __syncthreads();

    // ---- fragments (swizzled reads) ----
    const char* Ab = (const char*)smem;
    const char* Bb = (const char*)(smem + 2048);
    short8 ah[2], al[2], bh[4], bl[4];
    #pragma unroll
    for (int i = 0; i < 2; ++i) {
      const int ra  = i * 16 + fr;
      const int swa = (ra & 7) << 4;
      ah[i] = *(const short8*)(Ab + ra * 128 + ((quad << 4) ^ swa));
      al[i] = *(const short8*)(Ab + ra * 128 + ((64 | (quad << 4)) ^ swa));
    }
    #pragma unroll
    for (int j = 0; j < 4; ++j) {
      const int rb  = wc + j * 16 + fr;
      const int swb = (rb & 7) << 4;
      bh[j] = *(const short8*)(Bb + rb * 128 + ((quad << 4) ^ swb));
      bl[j] = *(const short8*)(Bb + rb * 128 + ((64 | (quad << 4)) ^ swb));
    }
    #pragma unroll
    for (int i = 0; i < 2; ++i)
      #pragma unroll
      for (int j = 0; j < 4; ++j) {
        acc[i][j] = __builtin_amdgcn_mfma_f32_16x16x32_bf16(ah[i], bh[j], acc[i][j], 0, 0, 0);
        acc[i][j] = __builtin_amdgcn_mfma_f32_16x16x32_bf16(ah[i], bl[j], acc[i][j], 0, 0, 0);
        acc[i][j] = __builtin_amdgcn_mfma_f32_16x16x32_bf16(al[i], bh[j], acc[i][j], 0, 0, 0);
      }
    __syncthreads();
  }

  // ---- epilogues; C/D layout: col=lane&15 group, row=quad*4+reg ----
  if constexpr (MODE == M_F32) {
    #pragma unroll
    for (int j = 0; j < 4; ++j) {
      const int colb = wc + j * 16 + fr;
      const float bv = bias ? bias[colb] : 0.f;
      #pragma unroll
      for (int i = 0; i < 2; ++i)
        #pragma unroll
        for (int r = 0; r < 4; ++r) {
          const int row = row0 + i * 16 + quad * 4 + r;
          C[(size_t)row * ldc + colb] = acc[i][j][r] + bv;
        }
    }
  } else if constexpr (MODE == M_PLANES) {
    #pragma unroll
    for (int j = 0; j < 4; ++j) {
      const int colb = wc + j * 16 + fr;
      #pragma unroll
      for (int i = 0; i < 2; ++i)
        #pragma unroll
        for (int r = 0; r < 4; ++r) {
          const int row = row0 + i * 16 + quad * 4 + r;
          split_pk(acc[i][j][r], opk, ldc, row, colb);   // ldc = rows of output
        }
    }
  } else if constexpr (MODE == M_RFFT) {
    #pragma unroll
    for (int j = 0; j < 4; ++j) {
      const int colb = wc + j * 16 + fr;
      #pragma unroll
      for (int i = 0; i < 2; ++i)
        #pragma unroll
        for (int r = 0; r < 4; ++r) {
          const int row = row0 + i * 16 + quad * 4 + r;
          const float v = acc[i][j][r];
          C[(size_t)row * ldc + colb] = v;
          const float w = __shfl_xor(v, 1, 64);
          if (!(lane & 1)) {
            const int bin = colb >> 1;
            const float mg = sqrtf(fmaxf(v * v + w * w, EPSF));
            split_pk(mg, opk, BN, row, bin);
          }
        }
    }
  } else if constexpr (MODE == M_EST) {
    #pragma unroll
    for (int j = 0; j < 4; ++j) {
      const int colg = wc + j * 16 + fr;   // bin index (0..383)
      const float bv = bias[colg];
      #pragma unroll
      for (int i = 0; i < 2; ++i)
        #pragma unroll
        for (int r = 0; r < 4; ++r) {
          const int row = row0 + i * 16 + quad * 4 + r;
          if (colg < NBIN) {
            const float m   = sigm(acc[i][j][r] + bv);
            const float mag = read_pk(auxpk, BN, row, colg);
            const float e   = m * mag;
            const float rr  = aux0[(size_t)row * 514 + 2 * colg];
            const float im  = aux0[(size_t)row * 514 + 2 * colg + 1];
            const float re = rr + EPSF, ie = im + EPSF;
            const float hyp = fmaxf(sqrtf(re * re + ie * ie), 1e-35f);
            split_pk(e * re / hyp, opk, BN, row, 2 * colg);
            split_pk(e * ie / hyp, opk, BN, row, 2 * colg + 1);
          } else if (colg < 272) {
            const int k0 = 2 * colg;
            opk[pkoff(BN, row, k0, 0)] = 0;     opk[pkoff(BN, row, k0, 1)] = 0;
            opk[pkoff(BN, row, k0 + 1, 0)] = 0; opk[pkoff(BN, row, k0 + 1, 1)] = 0;
          }
        }
    }
  } else if constexpr (MODE == M_DEC) {
    #pragma unroll
    for (int j = 0; j < 4; ++j) {
      const int colg = wc + j * 16 + fr;
      const float bv = bias[colg];
      #pragma unroll
      for (int i = 0; i < 2; ++i)
        #pragma unroll
        for (int r = 0; r < 4; ++r) {
          const int row = row0 + i * 16 + quad * 4 + r;
          const float v = sigm(acc[i][j][r] + bv) * aux0[(size_t)row * NE + colg];
          split_pk(v, opk, BN, row, colg);
        }
    }
  } else {
    // M_LSTM (WAVES=8 only): full 512 gate-cols in-block; Ep[32][512] f32
    float* Ep = (float*)smem;   // 64 KB <= staging LDS (68 KB)
    #pragma unroll
    for (int j = 0; j < 4; ++j) {
      const int cl = wc + j * 16 + fr;
      const float bv = bias[cl];
      #pragma unroll
      for (int i = 0; i < 2; ++i)
        #pragma unroll
        for (int r = 0; r < 4; ++r)
          Ep[(i * 16 + quad * 4 + r) * 512 + cl] = acc[i][j][r] + bv;
    }
    __syncthreads();
    #pragma unroll
    for (int k = 0; k < 4096 / NT; ++k) {
      const int cell = tid + NT * k;         // 0..4095 = 32 rows x 128 units
      const int rin  = cell >> 7;
      const int unit = cell & 127;
      const float* g = Ep + rin * 512 + ((unit >> 5) << 7) + (unit & 31);
      const float gi = g[0];
      const float gf = g[32];
      const float gc = g[64];
      const float go = g[96];
      const int row = row0 + rin;
      const size_t sidx = (size_t)row * NH + unit;
      const float cp = aux0[2 * sidx + 1];           // c from original state
      const float cn = sigm(gf) * cp + sigm(gi) * tanhf(gc);
      const float hn = sigm(go) * tanhf(cn);
      split_pk(hn, opk, BN, row, unit);
      float2 hc; hc.x = hn; hc.y = cn;
      *(float2*)(out0 + 2 * sidx) = hc;
    }
  }
}

// ================= consolidated prep: twiddles + weights + biases ==========
__device__ __forceinline__ void do_wconv_pk(const float* src, int M0, int K0,
                                            ushort* dst, int Mp, int Kp, int li){
  int r = li / Kp, k = li - r * Kp;
  float v = (r < M0 && k < K0) ? src[(size_t)r * K0 + k] : 0.f;
  split_pk(v, dst, Mp, r, k);
}
__device__ __forceinline__ void do_wconv_g_pk(const float* src, int K0,
                                              ushort* dst, int Kp, int li){
  int rp = li / Kp, k = li - rp * Kp;
  int y = rp >> 7, g = (rp >> 5) & 3, u = (y << 5) | (rp & 31);
  float v = (k < K0) ? src[(size_t)(g * 128 + u) * K0 + k] : 0.f;
  split_pk(v, dst, 512, rp, k);
}

__global__ void prep_all(
    const float* s1_wih1, const float* s1_whh1, const float* s1_wih2,
    const float* s1_whh2, const float* s1_dw,   const float* enc_w,
    const float* s2_wih1, const float* s2_whh1, const float* s2_wih2,
    const float* s2_whh2, const float* s2_dw,   const float* dec_w,
    const float* s1_bih1, const float* s1_bhh1, const float* s1_bih2,
    const float* s1_bhh2, const float* s1_db,
    const float* s2_bih1, const float* s2_bhh1, const float* s2_bih2,
    const float* s2_bhh2, const float* s2_db,
    ushort* fwdTpk, ushort* invTtpk,
    ushort* w11pk, ushort* wh1pk, ushort* w12pk, ushort* wh2pk,
    ushort* dw1pk, ushort* encwpk, ushort* w21pk, ushort* wh3pk,
    ushort* w22pk, ushort* wh4pk, ushort* dw2pk, ushort* decwpk,
    float* bg1, float* bg2, float* bm1, float* bg3, float* bg4, float* bm2)
{
  int idx = blockIdx.x * blockDim.x + threadIdx.x;
  if (idx < 262144) {              // fwdT [512 c][512 n]
    int c = idx >> 9, n = idx & 511;
    int k = c >> 1, m = (k * n) & 511;
    float th = (float)m * (6.283185307179586f / 512.0f);
    float s, co; sincosf(th, &s, &co);
    split_pk((c & 1) ? -s : co, fwdTpk, 512, c, n);
  } else if (idx < 589824) {       // invT^T [640 c][512 n]
    int li = idx - 262144;
    int c = li >> 9, n = li & 511;
    float v = 0.f;
    if (c < 512) {
      int k = c >> 1, m = (k * n) & 511;
      float th = (float)m * (6.283185307179586f / 512.0f);
      float s, co; sincosf(th, &s, &co);
      float w = (k == 0) ? (1.0f / 512.0f) : (2.0f / 512.0f);
      v = (c & 1) ? -w * s : w * co;
    } else if (c == 512) {
      v = ((n & 1) ? -1.0f : 1.0f) / 512.0f;
    }
    split_pk(v, invTtpk, 640, c, n);
  } else if (idx < 737280)  { do_wconv_g_pk(s1_wih1, 257, w11pk, 288, idx - 589824);
  } else if (idx < 802816)  { do_wconv_g_pk(s1_whh1, 128, wh1pk, 128, idx - 737280);
  } else if (idx < 868352)  { do_wconv_g_pk(s1_wih2, 128, w12pk, 128, idx - 802816);
  } else if (idx < 933888)  { do_wconv_g_pk(s1_whh2, 128, wh2pk, 128, idx - 868352);
  } else if (idx < 983040)  { do_wconv_pk(s1_dw, 257, 128, dw1pk, 384, 128, idx - 933888);
  } else if (idx < 1114112) { do_wconv_pk(enc_w, 256, 512, encwpk, 256, 512, idx - 983040);
  } else if (idx < 1245184) { do_wconv_g_pk(s2_wih1, 256, w21pk, 256, idx - 1114112);
  } else if (idx < 1310720) { do_wconv_g_pk(s2_whh1, 128, wh3pk, 128, idx - 1245184);
  } else if (idx < 1376256) { do_wconv_g_pk(s2_wih2, 128, w22pk, 128, idx - 1310720);
  } else if (idx < 1441792) { do_wconv_g_pk(s2_whh2, 128, wh4pk, 128, idx - 1376256);
  } else if (idx < 1474560) { do_wconv_pk(s2_dw, 256, 128, dw2pk, 256, 128, idx - 1441792);
  } else if (idx < 1605632) { do_wconv_pk(dec_w, 512, 256, decwpk, 512, 256, idx - 1474560);
  } else if (idx < 1606144) {      // bg1
    int rp = idx - 1605632;
    int y = rp >> 7, g = (rp >> 5) & 3, u = (y << 5) | (rp & 31);
    int sr = g * 128 + u;
    bg1[rp] = s1_bih1[sr] + s1_bhh1[sr];
  } else if (idx < 1606656) {      // bg2
    int rp = idx - 1606144;
    int y = rp >> 7, g = (rp >> 5) & 3, u = (y << 5) | (rp & 31);
    int sr = g * 128 + u;
    bg2[rp] = s1_bih2[sr] + s1_bhh2[sr];
  } else if (idx < 1607040) {      // bm1 (pad 257 -> 384)
    int i = idx - 1606656;
    bm1[i] = (i < 257) ? s1_db[i] : 0.f;
  } else if (idx < 1607552) {      // bg3
    int rp = idx - 1607040;
    int y = rp >> 7, g = (rp >> 5) & 3, u = (y << 5) | (rp & 31);
    int sr = g * 128 + u;
    bg3[rp] = s2_bih1[sr] + s2_bhh1[sr];
  } else if (idx < 1608064) {      // bg4
    int rp = idx - 1607552;
    int y = rp >> 7, g = (rp >> 5) & 3, u = (y << 5) | (rp & 31);
    int sr = g * 128 + u;
    bg4[rp] = s2_bih2[sr] + s2_bhh2[sr];
  } else if (idx < 1608320) {      // bm2
    int i = idx - 1608064;
    bm2[i] = s2_db[i];
  }
}

// ================= input prep: LDS-tiled transpose + fused Nyquist =========
__global__ __launch_bounds__(256)
void input_prep(const float* __restrict__ x, ushort* __restrict__ XSpk,
                const float* __restrict__ st1,
                ushort* __restrict__ h1pk, ushort* __restrict__ h2pk,
                const float* __restrict__ st2,
                ushort* __restrict__ h3pk, ushort* __restrict__ h4pk,
                float* __restrict__ RI, ushort* __restrict__ magpk)
{
  __shared__ float L[16 * 516];          // x: [16][516]; state: [16][260]
  const int tid = threadIdx.x;
  const int b   = blockIdx.x;
  if (b < BN / 16) {
    const int row0 = b * 16;
    #pragma unroll
    for (int i = 0; i < 8; ++i) {        // 8192 f32, 4KB contiguous/instr
      int g = i * 1024 + tid * 4;
      int row = g >> 9, col = g & 511;
      *(float4v*)&L[row * 516 + col] = *(const float4v*)(x + (size_t)row0 * 512 + g);
    }
    __syncthreads();
    // ---- fused Nyquist: s = sum_n x[row][n] * (-1)^n ----
    if (tid < 128) {
      int row = tid >> 3, seg = tid & 7;
      const float* Lr = &L[row * 516 + seg * 64];
      float s = 0.f;
      #pragma unroll
      for (int i = 0; i < 64; i += 4) {
        float4v v4 = *(const float4v*)(Lr + i);
        s += (v4[0] - v4[1]) + (v4[2] - v4[3]);
      }
      s += __shfl_xor(s, 1, 64);
      s += __shfl_xor(s, 2, 64);
      s += __shfl_xor(s, 4, 64);
      if (seg == 0) {
        int grow = row0 + row;
        RI[(size_t)grow * 514 + 512] = s;
        RI[(size_t)grow * 514 + 513] = 0.f;
        split_pk(sqrtf(fmaxf(s * s, EPSF)), magpk, BN, grow, 256);
      }
    }
    // zero mag bins 257..287 for these rows
    #pragma unroll 1
    for (int u = tid; u < 16 * 31; u += 256) {
      int row = row0 + (u / 31), bin = 257 + (u % 31);
      magpk[pkoff(BN, row, bin, 0)] = 0;
      magpk[pkoff(BN, row, bin, 1)] = 0;
    }
    // ---- packed-layout stores (kt 0..15, vectorized LDS reads) ----
    #pragma unroll
    for (int i = 0; i < 8; ++i) {
      int u = i * 256 + tid;             // 0..2047
      int kt = u >> 7, unit = u & 127;
      int row = unit >> 3, pslot = unit & 7;
      int ls = pslot ^ (row & 7);
      const float* src = &L[row * 516 + kt * 32 + (ls & 3) * 8];
      float4v a = *(const float4v*)(src);
      float4v c = *(const float4v*)(src + 4);
      short8 out;
      if (ls < 4) {
        #pragma unroll
        for (int e = 0; e < 4; ++e) out[e]     = (short)f2b(a[e]);
        #pragma unroll
        for (int e = 0; e < 4; ++e) out[4 + e] = (short)f2b(c[e]);
      } else {
        #pragma unroll
        for (int e = 0; e < 4; ++e) {
          ushort h = f2b(a[e]);
          out[e] = (short)f2b(a[e] - b2f(h));
        }
        #pragma unroll
        for (int e = 0; e < 4; ++e) {
          ushort h = f2b(c[e]);
          out[4 + e] = (short)f2b(c[e] - b2f(h));
        }
      }
      *(short8*)(XSpk + (size_t)kt * ((size_t)BN << 6) +
                 ((size_t)(row0 + row) << 6) + pslot * 8) = out;
    }
    // chunk 16: zeros (128 units)
    if (tid < 128) {
      int row = tid >> 3, pslot = tid & 7;
      short8 z;
      #pragma unroll
      for (int e = 0; e < 8; ++e) z[e] = 0;
      *(short8*)(XSpk + (size_t)16 * ((size_t)BN << 6) +
                 ((size_t)(row0 + row) << 6) + pslot * 8) = z;
    }
  } else {
    const int lb    = b - BN / 16;
    const int layer = lb >> 10;          // BN/16 = 1024 blocks per layer
    const int row0  = (lb & 1023) * 16;
    const float* st = (layer < 2) ? st1 : st2;
    const float* sp = st + ((layer & 1) ? (size_t)BN * NH * 2 : 0) +
                      (size_t)row0 * 256;
    ushort* hp = (layer == 0) ? h1pk : (layer == 1) ? h2pk :
                 (layer == 2) ? h3pk : h4pk;
    #pragma unroll
    for (int i = 0; i < 4; ++i) {        // 4096 f32 (h,c interleaved)
      int g = i * 1024 + tid * 4;
      int row = g >> 8, col = g & 255;
      *(float4v*)&L[row * 260 + col] = *(const float4v*)(sp + g);
    }
    __syncthreads();
    #pragma unroll
    for (int it = 0; it < 2; ++it) {
      int u = it * 256 + tid;            // 0..511 = 4 chunks x 128 units
      int kt = u >> 7, unit = u & 127;
      int row = unit >> 3, pslot = unit & 7;
      int ls = pslot ^ (row & 7);
      const float* src = &L[row * 260 + (kt * 32 + (ls & 3) * 8) * 2];
      float4v v0 = *(const float4v*)(src);
      float4v v1 = *(const float4v*)(src + 4);
      float4v v2 = *(const float4v*)(src + 8);
      float4v v3 = *(const float4v*)(src + 12);
      float hvals[8] = { v0[0], v0[2], v1[0], v1[2], v2[0], v2[2], v3[0], v3[2] };
      short8 out;
      if (ls < 4) {
        #pragma unroll
        for (int e = 0; e < 8; ++e) out[e] = (short)f2b(hvals[e]);
      } else {
        #pragma unroll
        for (int e = 0; e < 8; ++e) {
          ushort h = f2b(hvals[e]);
          out[e] = (short)f2b(hvals[e] - b2f(h));
        }
      }
      *(short8*)(hp + (size_t)kt * ((size_t)BN << 6) +
                 ((size_t)(row0 + row) << 6) + pslot * 8) = out;
    }
  }
}

// LayerNorm over 256 -> packed ENCN
__global__ void ln_kernel(const float* __restrict__ ENC,
                          const float* __restrict__ gamma,
                          const float* __restrict__ beta,
                          ushort* __restrict__ opk){
  int row = blockIdx.x;
  int t = threadIdx.x;   // 64; thread handles cols 4t..4t+3
  const float* e = ENC + (size_t)row * NE;
  float v[4]; float s = 0.f;
  #pragma unroll
  for (int i = 0; i < 4; ++i) { v[i] = e[4 * t + i]; s += v[i]; }
  #pragma unroll
  for (int off = 32; off >= 1; off >>= 1) s += __shfl_xor(s, off, 64);
  float mean = s * (1.0f / NE);
  float d[4]; float ss = 0.f;
  #pragma unroll
  for (int i = 0; i < 4; ++i) { d[i] = v[i] - mean; ss += d[i] * d[i]; }
  #pragma unroll
  for (int off = 32; off >= 1; off >>= 1) ss += __shfl_xor(ss, off, 64);
  float inv = 1.0f / sqrtf(ss * (1.0f / NE) + LNEPS);
  #pragma unroll
  for (int i = 0; i < 4; ++i) {
    int col = 4 * t + i;
    float o = d[i] * inv * gamma[col] + beta[col];
    split_pk(o, opk, BN, row, col);
  }
}

// ================= launch =================
extern "C" void kernel_launch(void* const* d_in, const int* in_sizes, int n_in,
                              void* d_out, int out_size, void* d_ws, size_t ws_size,
                              hipStream_t stream)
{
  const float* x       = (const float*)d_in[0];
  const float* st1     = (const float*)d_in[1];
  const float* st2     = (const float*)d_in[2];
  const float* s1_wih1 = (const float*)d_in[3];
  const float* s1_whh1 = (const float*)d_in[4];
  const float* s1_bih1 = (const float*)d_in[5];
  const float* s1_bhh1 = (const float*)d_in[6];
  const float* s1_wih2 = (const float*)d_in[7];
  const float* s1_whh2 = (const float*)d_in[8];
  const float* s1_bih2 = (const float*)d_in[9];
  const float* s1_bhh2 = (const float*)d_in[10];
  const float* s1_dw   = (const float*)d_in[11];
  const float* s1_db   = (const float*)d_in[12];
  const float* enc_w   = (const float*)d_in[13];
  const float* ln_g    = (const float*)d_in[14];
  const float* ln_b    = (const float*)d_in[15];
  const float* s2_wih1 = (const float*)d_in[16];
  const float* s2_whh1 = (const float*)d_in[17];
  const float* s2_bih1 = (const float*)d_in[18];
  const float* s2_bhh1 = (const float*)d_in[19];
  const float* s2_wih2 = (const float*)d_in[20];
  const float* s2_whh2 = (const float*)d_in[21];
  const float* s2_bih2 = (const float*)d_in[22];
  const float* s2_bhh2 = (const float*)d_in[23];
  const float* s2_dw   = (const float*)d_in[24];
  const float* s2_db   = (const float*)d_in[25];
  const float* dec_w   = (const float*)d_in[26];

  float* out_dec = (float*)d_out;
  float* out_st1 = out_dec + (size_t)BN * NFFT;
  float* out_st2 = out_st1 + (size_t)2 * BN * NH * 2;

  // ---- workspace ----
  char* base = (char*)d_ws;
  size_t off = 0;
  auto alloc = [&](size_t bytes) -> void* {
    off = (off + 255) & ~(size_t)255;
    void* p = base + off;
    off += bytes;
    return p;
  };
  auto pkbytes = [](int rows, int nk) -> size_t {
    return (size_t)nk * rows * 64 * 2;
  };
  ushort* fwdTpk  = (ushort*)alloc(pkbytes(512, 16));
  ushort* invTtpk = (ushort*)alloc(pkbytes(640, 16));
  ushort* MEpk    = (ushort*)alloc(pkbytes(256, 20));
  ushort* XSpk    = (ushort*)alloc(pkbytes(BN, 17));
  float*  RI      = (float*) alloc((size_t)BN * 514 * 4);
  ushort* magpk   = (ushort*)alloc(pkbytes(BN, 9));
  float*  ENC     = (float*) alloc((size_t)BN * NE * 4);
  ushort* ENCNpk  = (ushort*)alloc(pkbytes(BN, 8));
  ushort* Dpk     = (ushort*)alloc(pkbytes(BN, 8));
  ushort* h1pk    = (ushort*)alloc(pkbytes(BN, 4));
  ushort* h2pk    = (ushort*)alloc(pkbytes(BN, 4));
  ushort* h3pk    = (ushort*)alloc(pkbytes(BN, 4));
  ushort* h4pk    = (ushort*)alloc(pkbytes(BN, 4));
  ushort* h1npk   = (ushort*)alloc(pkbytes(BN, 4));
  ushort* h2npk   = (ushort*)alloc(pkbytes(BN, 4));
  ushort* w11pk   = (ushort*)alloc(pkbytes(512, 9));
  ushort* wh1pk   = (ushort*)alloc(pkbytes(512, 4));
  ushort* w12pk   = (ushort*)alloc(pkbytes(512, 4));
  ushort* wh2pk   = (ushort*)alloc(pkbytes(512, 4));
  ushort* dw1pk   = (ushort*)alloc(pkbytes(384, 4));
  ushort* encwpk  = (ushort*)alloc(pkbytes(256, 16));
  ushort* w21pk   = (ushort*)alloc(pkbytes(512, 8));
  ushort* wh3pk   = (ushort*)alloc(pkbytes(512, 4));
  ushort* w22pk   = (ushort*)alloc(pkbytes(512, 4));
  ushort* wh4pk   = (ushort*)alloc(pkbytes(512, 4));
  ushort* dw2pk   = (ushort*)alloc(pkbytes(256, 4));
  ushort* decwpk  = (ushort*)alloc(pkbytes(512, 8));
  float* bg1 = (float*)alloc(512*4); float* bg2 = (float*)alloc(512*4);
  float* bm1 = (float*)alloc(384*4);
  float* bg3 = (float*)alloc(512*4); float* bg4 = (float*)alloc(512*4);
  float* bm2 = (float*)alloc(256*4);
  (void)ws_size; (void)in_sizes; (void)n_in; (void)out_size;

  const dim3 blk(256);

  // ---- one consolidated prep launch (twiddles + weights + biases) ----
  prep_all<<<(1608320 + 255) / 256, blk, 0, stream>>>(
      s1_wih1, s1_whh1, s1_wih2, s1_whh2, s1_dw, enc_w,
      s2_wih1, s2_whh1, s2_wih2, s2_whh2, s2_dw, dec_w,
      s1_bih1, s1_bhh1, s1_bih2, s1_bhh2, s1_db,
      s2_bih1, s2_bhh1, s2_bih2, s2_bhh2, s2_db,
      fwdTpk, invTtpk,
      w11pk, wh1pk, w12pk, wh2pk, dw1pk, encwpk, w21pk, wh3pk,
      w22pk, wh4pk, dw2pk, decwpk,
      bg1, bg2, bm1, bg3, bg4, bm2);

  // ---- ME = enc_w x invT (256x640, K=512) -> packed (folds irfft into enc) ----
  mfma_gemm<M_PLANES, 10><<<8, 640, 0, stream>>>(encwpk, 256, 16, invTtpk, 640,
      nullptr, 0, nullptr, 0,
      nullptr, nullptr, 256, nullptr, nullptr, nullptr, MEpk);

  // ---- one consolidated input prep (LDS transpose + fused Nyquist) ----
  input_prep<<<BN / 16 + 4 * (BN / 16), blk, 0, stream>>>(
      x, XSpk, st1, h1pk, h2pk, st2, h3pk, h4pk, RI, magpk);

  // ---- rfft (+fused magphase) ----
  mfma_gemm<M_RFFT, 8><<<BN / 32, 512, 0, stream>>>(XSpk, BN, 16, fwdTpk, 512,
      nullptr, 0, nullptr, 0,
      nullptr, RI, 514, nullptr, nullptr, nullptr, magpk);

  // ---- sep block 1 (fused LSTM epilogues; c read from st directly) ----
  mfma_gemm<M_LSTM, 8><<<BN / 32, 512, 0, stream>>>(magpk, BN, 9, w11pk, 512,
      h1pk, 4, wh1pk, 512,
      bg1, nullptr, 0, st1, nullptr, out_st1, h1npk);
  mfma_gemm<M_LSTM, 8><<<BN / 32, 512, 0, stream>>>(h1npk, BN, 4, w12pk, 512,
      h2pk, 4, wh2pk, 512,
      bg2, nullptr, 0, st1 + (size_t)BN*NH*2, nullptr,
      out_st1 + (size_t)BN*NH*2, h2npk);
  // ---- mask1 + fused est_build -> XS packed ----
  mfma_gemm<M_EST, 6><<<BN / 32, 384, 0, stream>>>(h2npk, BN, 4, dw1pk, 384,
      nullptr, 0, nullptr, 0,
      bm1, nullptr, 0, RI, magpk, nullptr, XSpk);

  // ---- encoder (irfft folded via ME) + LN ----
  mfma_gemm<M_F32, 4><<<BN / 32, 256, 0, stream>>>(XSpk, BN, 17, MEpk, 256,
      nullptr, 0, nullptr, 0,
      nullptr, ENC, 256, nullptr, nullptr, nullptr, nullptr);
  ln_kernel<<<BN, 64, 0, stream>>>(ENC, ln_g, ln_b, ENCNpk);

  // ---- sep block 2 ----
  mfma_gemm<M_LSTM, 8><<<BN / 32, 512, 0, stream>>>(ENCNpk, BN, 8, w21pk, 512,
      h3pk, 4, wh3pk, 512,
      bg3, nullptr, 0, st2, nullptr, out_st2, h1npk);
  mfma_gemm<M_LSTM, 8><<<BN / 32, 512, 0, stream>>>(h1npk, BN, 4, w22pk, 512,
      h4pk, 4, wh4pk, 512,
      bg4, nullptr, 0, st2 + (size_t)BN*NH*2, nullptr,
      out_st2 + (size_t)BN*NH*2, h2npk);
  // ---- mask2 + fused dec_in -> D packed ----
  mfma_gemm<M_DEC, 4><<<BN / 32, 256, 0, stream>>>(h2npk, BN, 4, dw2pk, 256,
      nullptr, 0, nullptr, 0,
      bm2, nullptr, 0, ENC, nullptr, nullptr, Dpk);

  // ---- decoder ----
  mfma_gemm<M_F32, 8><<<BN / 32, 512, 0, stream>>>(Dpk, BN, 8, decwpk, 512,
      nullptr, 0, nullptr, 0,
      nullptr, out_dec, 512, nullptr, nullptr, nullptr, nullptr);
}

// Round 18
// 378.333 us; speedup vs baseline: 1.0219x; 1.0219x over previous
//
#include <hip/hip_runtime.h>
#include <hip/hip_bf16.h>
#include <math.h>

static constexpr int BN   = 16384;
static constexpr int NFFT = 512;
static constexpr int NBIN = 257;
static constexpr int NH   = 128;
static constexpr int NE   = 256;
static constexpr float EPSF  = 1.1920929e-07f;
static constexpr float LNEPS = 1e-07f;

using short8  = __attribute__((ext_vector_type(8))) short;
using float4v = __attribute__((ext_vector_type(4))) float;

__device__ __forceinline__ float sigm(float x){ return 1.0f/(1.0f+expf(-x)); }
__device__ __forceinline__ ushort f2b(float v){
  __hip_bfloat16 b = __float2bfloat16(v);
  return *reinterpret_cast<ushort*>(&b);
}
__device__ __forceinline__ float b2f(ushort u){
  __hip_bfloat16 b = *reinterpret_cast<__hip_bfloat16*>(&u);
  return __bfloat162float(b);
}

// ---- packed staging-ready layout ----
// matrix [rows][K] stored as chunks: chunk kt (32 k) x row -> 128B:
// 8 slots x 16B; slot p at row r holds LOGICAL slot p^(r&7);
// logical slots 0..3 = hi bf16 of k sub-chunks, 4..7 = lo bf16.
__device__ __forceinline__ size_t pkoff(int rows, int row, int k, int lo){
  const int ls = ((((k >> 3) & 3) | (lo << 2)) ^ (row & 7));
  return (size_t)(k >> 5) * ((size_t)rows << 6) + ((size_t)row << 6) + (ls << 3) + (k & 7);
}
__device__ __forceinline__ void split_pk(float v, ushort* base, int rows, int row, int k){
  ushort h = f2b(v);
  base[pkoff(rows, row, k, 0)] = h;
  base[pkoff(rows, row, k, 1)] = f2b(v - b2f(h));
}
__device__ __forceinline__ float read_pk(const ushort* base, int rows, int row, int k){
  return b2f(base[pkoff(rows, row, k, 0)]) + b2f(base[pkoff(rows, row, k, 1)]);
}

__device__ __forceinline__ void gload16(const ushort* g, ushort* l){
  __builtin_amdgcn_global_load_lds(
      (const __attribute__((address_space(1))) unsigned int*)g,
      (__attribute__((address_space(3))) unsigned int*)l,
      16, 0, 0);
}

// epilogue modes
enum { M_F32 = 0, M_PLANES = 1, M_LSTM = 2, M_EST = 3, M_DEC = 4, M_RFFT = 5 };

// ======= MFMA bf16x2 NT GEMM, BM=128 / BNc=128, packed operands ===========
// C[row][col] = sum_k A[row][k]*B[col][k] (+ optional phase2 A2/B2)
// 4 waves in 2x2 grid, each 64x64 (acc[4][4]). 32KB LDS, 8 gload16/wave/iter
// (each 1KB contiguous). Grid = (BN/128) x ncolblocks — halves aggregate
// staged bytes vs BM=64 (B restaged by half as many blocks).
// MODE_LSTM expects gate-PERMUTED weights/bias: col' = 128*(u>>5)+32*g+(u&31);
// col block y holds units 32y..32y+31, all 4 gates. aux0 = ORIGINAL state
// buffer (h,c interleaved); c = aux0[2*idx+1].
template<int MODE>
__global__ __launch_bounds__(256)
void mfma_gemm(const ushort* __restrict__ Apk, int MA, int nkA,
               const ushort* __restrict__ Bpk, int MB,
               const ushort* __restrict__ A2pk, int nkA2,
               const ushort* __restrict__ B2pk, int MB2,
               const float* __restrict__ bias,
               float* __restrict__ C, int ldc,
               const float* __restrict__ aux0,   // LSTM: st base | EST: RI | DEC: ENC
               const ushort* __restrict__ auxpk, // EST: mag packed
               float* __restrict__ out0,         // LSTM: out_state (h,c pairs)
               ushort* __restrict__ opk)         // packed output
{
  __shared__ ushort smem[16384];         // A[128][64] | B[128][64] = 32 KB
  const int tid  = threadIdx.x;
  const int row0 = blockIdx.x * 128;
  const int col0 = blockIdx.y * 128;
  const int lane = tid & 63;
  const int wv   = tid >> 6;
  const int wr   = (wv >> 1) * 64;
  const int wc   = (wv & 1) * 64;
  const int fr   = lane & 15;
  const int quad = lane >> 4;

  float4v acc[4][4];
  #pragma unroll
  for (int i = 0; i < 4; ++i)
    #pragma unroll
    for (int j = 0; j < 4; ++j)
      acc[i][j] = float4v{0.f, 0.f, 0.f, 0.f};

  const int nt0 = nkA;
  const int nt1 = A2pk ? nkA2 : 0;
  const int nt  = nt0 + nt1;

  const size_t astr  = (size_t)MA << 6;
  const size_t bstr  = (size_t)MB << 6;
  const size_t bstr2 = (size_t)MB2 << 6;
  size_t abase[4], bbase[4];
  #pragma unroll
  for (int s = 0; s < 4; ++s) {
    abase[s] = ((size_t)(row0 + (wv * 4 + s) * 8) << 6) + lane * 8;
    bbase[s] = ((size_t)(col0 + (wv * 4 + s) * 8) << 6) + lane * 8;
  }

  #pragma unroll 1
  for (int t = 0; t < nt; ++t) {
    const ushort* Ap = (t < nt0) ? (Apk + (size_t)t * astr)
                                 : (A2pk + (size_t)(t - nt0) * astr);
    const ushort* Bp = (t < nt0) ? (Bpk + (size_t)t * bstr)
                                 : (B2pk + (size_t)(t - nt0) * bstr2);
    #pragma unroll
    for (int s = 0; s < 4; ++s) {
      gload16(Ap + abase[s], &smem[(wv * 4 + s) * 512]);
      gload16(Bp + bbase[s], &smem[8192 + (wv * 4 + s) * 512]);
    }
    asm volatile("s_waitcnt vmcnt(0)" ::: "memory");
    __syncthreads();

    // ---- fragments (swizzled reads) ----
    const char* Ab = (const char*)smem;
    const char* Bb = (const char*)(smem + 8192);
    short8 ah[4], al[4], bh[4], bl[4];
    #pragma unroll
    for (int i = 0; i < 4; ++i) {
      const int ra  = wr + i * 16 + fr;
      const int swa = (ra & 7) << 4;
      ah[i] = *(const short8*)(Ab + ra * 128 + ((quad << 4) ^ swa));
      al[i] = *(const short8*)(Ab + ra * 128 + ((64 | (quad << 4)) ^ swa));
      const int rb  = wc + i * 16 + fr;
      const int swb = (rb & 7) << 4;
      bh[i] = *(const short8*)(Bb + rb * 128 + ((quad << 4) ^ swb));
      bl[i] = *(const short8*)(Bb + rb * 128 + ((64 | (quad << 4)) ^ swb));
    }
    #pragma unroll
    for (int i = 0; i < 4; ++i)
      #pragma unroll
      for (int j = 0; j < 4; ++j) {
        acc[i][j] = __builtin_amdgcn_mfma_f32_16x16x32_bf16(ah[i], bh[j], acc[i][j], 0, 0, 0);
        acc[i][j] = __builtin_amdgcn_mfma_f32_16x16x32_bf16(ah[i], bl[j], acc[i][j], 0, 0, 0);
        acc[i][j] = __builtin_amdgcn_mfma_f32_16x16x32_bf16(al[i], bh[j], acc[i][j], 0, 0, 0);
      }
    __syncthreads();
  }

  // ---- epilogues; C/D layout: col=lane&15 group, row=quad*4+reg ----
  if constexpr (MODE == M_F32) {
    #pragma unroll
    for (int j = 0; j < 4; ++j) {
      const int colb = col0 + wc + j * 16 + fr;
      const float bv = bias ? bias[colb] : 0.f;
      #pragma unroll
      for (int i = 0; i < 4; ++i)
        #pragma unroll
        for (int r = 0; r < 4; ++r) {
          const int row = row0 + wr + i * 16 + quad * 4 + r;
          C[(size_t)row * ldc + colb] = acc[i][j][r] + bv;
        }
    }
  } else if constexpr (MODE == M_PLANES) {
    #pragma unroll
    for (int j = 0; j < 4; ++j) {
      const int colb = col0 + wc + j * 16 + fr;
      #pragma unroll
      for (int i = 0; i < 4; ++i)
        #pragma unroll
        for (int r = 0; r < 4; ++r) {
          const int row = row0 + wr + i * 16 + quad * 4 + r;
          split_pk(acc[i][j][r], opk, ldc, row, colb);   // ldc = rows of output
        }
    }
  } else if constexpr (MODE == M_RFFT) {
    #pragma unroll
    for (int j = 0; j < 4; ++j) {
      const int colb = col0 + wc + j * 16 + fr;
      #pragma unroll
      for (int i = 0; i < 4; ++i)
        #pragma unroll
        for (int r = 0; r < 4; ++r) {
          const int row = row0 + wr + i * 16 + quad * 4 + r;
          const float v = acc[i][j][r];
          C[(size_t)row * ldc + colb] = v;
          const float w = __shfl_xor(v, 1, 64);
          if (!(lane & 1)) {
            const int bin = colb >> 1;
            const float mg = sqrtf(fmaxf(v * v + w * w, EPSF));
            split_pk(mg, opk, BN, row, bin);
          }
        }
    }
  } else if constexpr (MODE == M_EST) {
    #pragma unroll
    for (int j = 0; j < 4; ++j) {
      const int colg = col0 + wc + j * 16 + fr;   // bin index
      const float bv = bias[colg];
      #pragma unroll
      for (int i = 0; i < 4; ++i)
        #pragma unroll
        for (int r = 0; r < 4; ++r) {
          const int row = row0 + wr + i * 16 + quad * 4 + r;
          if (colg < NBIN) {
            const float m   = sigm(acc[i][j][r] + bv);
            const float mag = read_pk(auxpk, BN, row, colg);
            const float e   = m * mag;
            const float rr  = aux0[(size_t)row * 514 + 2 * colg];
            const float im  = aux0[(size_t)row * 514 + 2 * colg + 1];
            const float re = rr + EPSF, ie = im + EPSF;
            const float hyp = fmaxf(sqrtf(re * re + ie * ie), 1e-35f);
            split_pk(e * re / hyp, opk, BN, row, 2 * colg);
            split_pk(e * ie / hyp, opk, BN, row, 2 * colg + 1);
          } else if (colg < 272) {
            const int k0 = 2 * colg;
            opk[pkoff(BN, row, k0, 0)] = 0;     opk[pkoff(BN, row, k0, 1)] = 0;
            opk[pkoff(BN, row, k0 + 1, 0)] = 0; opk[pkoff(BN, row, k0 + 1, 1)] = 0;
          }
        }
    }
  } else if constexpr (MODE == M_DEC) {
    #pragma unroll
    for (int j = 0; j < 4; ++j) {
      const int colg = col0 + wc + j * 16 + fr;
      const float bv = bias[colg];
      #pragma unroll
      for (int i = 0; i < 4; ++i)
        #pragma unroll
        for (int r = 0; r < 4; ++r) {
          const int row = row0 + wr + i * 16 + quad * 4 + r;
          const float v = sigm(acc[i][j][r] + bv) * aux0[(size_t)row * NE + colg];
          split_pk(v, opk, BN, row, colg);
        }
    }
  } else {
    // M_LSTM: block's 128 cols = units ub..ub+31, gates 0..3 (permuted)
    float* Ep = (float*)smem;   // 64 rows x 128 gate-cols f32 = 32 KB
    const int ub = blockIdx.y << 5;
    #pragma unroll 1
    for (int p = 0; p < 2; ++p) {
      __syncthreads();
      if (wr == p * 64) {
        #pragma unroll
        for (int j = 0; j < 4; ++j) {
          const int cl = wc + j * 16 + fr;
          const float bv = bias[col0 + cl];
          #pragma unroll
          for (int i = 0; i < 4; ++i)
            #pragma unroll
            for (int r = 0; r < 4; ++r)
              Ep[(i * 16 + quad * 4 + r) * 128 + cl] = acc[i][j][r] + bv;
        }
      }
      __syncthreads();
      #pragma unroll
      for (int k = 0; k < 8; ++k) {
        const int cell = tid + 256 * k;        // 0..2047 = 64 rows x 32 units
        const int ul = cell & 31;
        const int er = cell >> 5;              // 0..63
        const int row = row0 + p * 64 + er;
        const int unit = ub + ul;
        const float gi = Ep[er * 128 + ul];
        const float gf = Ep[er * 128 + 32 + ul];
        const float gc = Ep[er * 128 + 64 + ul];
        const float go = Ep[er * 128 + 96 + ul];
        const size_t sidx = (size_t)row * NH + unit;
        const float cp = aux0[2 * sidx + 1];   // c from original state
        const float cn = sigm(gf) * cp + sigm(gi) * tanhf(gc);
        const float hn = sigm(go) * tanhf(cn);
        split_pk(hn, opk, BN, row, unit);
        float2 hc; hc.x = hn; hc.y = cn;
        *(float2*)(out0 + 2 * sidx) = hc;
      }
    }
  }
}

// ================= consolidated prep: twiddles + weights + biases ==========
__device__ __forceinline__ void do_wconv_pk(const float* src, int M0, int K0,
                                            ushort* dst, int Mp, int Kp, int li){
  int r = li / Kp, k = li - r * Kp;
  float v = (r < M0 && k < K0) ? src[(size_t)r * K0 + k] : 0.f;
  split_pk(v, dst, Mp, r, k);
}
__device__ __forceinline__ void do_wconv_g_pk(const float* src, int K0,
                                              ushort* dst, int Kp, int li){
  int rp = li / Kp, k = li - rp * Kp;
  int y = rp >> 7, g = (rp >> 5) & 3, u = (y << 5) | (rp & 31);
  float v = (k < K0) ? src[(size_t)(g * 128 + u) * K0 + k] : 0.f;
  split_pk(v, dst, 512, rp, k);
}

__global__ void prep_all(
    const float* s1_wih1, const float* s1_whh1, const float* s1_wih2,
    const float* s1_whh2, const float* s1_dw,   const float* enc_w,
    const float* s2_wih1, const float* s2_whh1, const float* s2_wih2,
    const float* s2_whh2, const float* s2_dw,   const float* dec_w,
    const float* s1_bih1, const float* s1_bhh1, const float* s1_bih2,
    const float* s1_bhh2, const float* s1_db,
    const float* s2_bih1, const float* s2_bhh1, const float* s2_bih2,
    const float* s2_bhh2, const float* s2_db,
    ushort* fwdTpk, ushort* invTtpk,
    ushort* w11pk, ushort* wh1pk, ushort* w12pk, ushort* wh2pk,
    ushort* dw1pk, ushort* encwpk, ushort* w21pk, ushort* wh3pk,
    ushort* w22pk, ushort* wh4pk, ushort* dw2pk, ushort* decwpk,
    float* bg1, float* bg2, float* bm1, float* bg3, float* bg4, float* bm2)
{
  int idx = blockIdx.x * blockDim.x + threadIdx.x;
  if (idx < 262144) {              // fwdT [512 c][512 n]
    int c = idx >> 9, n = idx & 511;
    int k = c >> 1, m = (k * n) & 511;
    float th = (float)m * (6.283185307179586f / 512.0f);
    float s, co; sincosf(th, &s, &co);
    split_pk((c & 1) ? -s : co, fwdTpk, 512, c, n);
  } else if (idx < 589824) {       // invT^T [640 c][512 n]
    int li = idx - 262144;
    int c = li >> 9, n = li & 511;
    float v = 0.f;
    if (c < 512) {
      int k = c >> 1, m = (k * n) & 511;
      float th = (float)m * (6.283185307179586f / 512.0f);
      float s, co; sincosf(th, &s, &co);
      float w = (k == 0) ? (1.0f / 512.0f) : (2.0f / 512.0f);
      v = (c & 1) ? -w * s : w * co;
    } else if (c == 512) {
      v = ((n & 1) ? -1.0f : 1.0f) / 512.0f;
    }
    split_pk(v, invTtpk, 640, c, n);
  } else if (idx < 737280)  { do_wconv_g_pk(s1_wih1, 257, w11pk, 288, idx - 589824);
  } else if (idx < 802816)  { do_wconv_g_pk(s1_whh1, 128, wh1pk, 128, idx - 737280);
  } else if (idx < 868352)  { do_wconv_g_pk(s1_wih2, 128, w12pk, 128, idx - 802816);
  } else if (idx < 933888)  { do_wconv_g_pk(s1_whh2, 128, wh2pk, 128, idx - 868352);
  } else if (idx < 983040)  { do_wconv_pk(s1_dw, 257, 128, dw1pk, 384, 128, idx - 933888);
  } else if (idx < 1114112) { do_wconv_pk(enc_w, 256, 512, encwpk, 256, 512, idx - 983040);
  } else if (idx < 1245184) { do_wconv_g_pk(s2_wih1, 256, w21pk, 256, idx - 1114112);
  } else if (idx < 1310720) { do_wconv_g_pk(s2_whh1, 128, wh3pk, 128, idx - 1245184);
  } else if (idx < 1376256) { do_wconv_g_pk(s2_wih2, 128, w22pk, 128, idx - 1310720);
  } else if (idx < 1441792) { do_wconv_g_pk(s2_whh2, 128, wh4pk, 128, idx - 1376256);
  } else if (idx < 1474560) { do_wconv_pk(s2_dw, 256, 128, dw2pk, 256, 128, idx - 1441792);
  } else if (idx < 1605632) { do_wconv_pk(dec_w, 512, 256, decwpk, 512, 256, idx - 1474560);
  } else if (idx < 1606144) {      // bg1
    int rp = idx - 1605632;
    int y = rp >> 7, g = (rp >> 5) & 3, u = (y << 5) | (rp & 31);
    int sr = g * 128 + u;
    bg1[rp] = s1_bih1[sr] + s1_bhh1[sr];
  } else if (idx < 1606656) {      // bg2
    int rp = idx - 1606144;
    int y = rp >> 7, g = (rp >> 5) & 3, u = (y << 5) | (rp & 31);
    int sr = g * 128 + u;
    bg2[rp] = s1_bih2[sr] + s1_bhh2[sr];
  } else if (idx < 1607040) {      // bm1 (pad 257 -> 384)
    int i = idx - 1606656;
    bm1[i] = (i < 257) ? s1_db[i] : 0.f;
  } else if (idx < 1607552) {      // bg3
    int rp = idx - 1607040;
    int y = rp >> 7, g = (rp >> 5) & 3, u = (y << 5) | (rp & 31);
    int sr = g * 128 + u;
    bg3[rp] = s2_bih1[sr] + s2_bhh1[sr];
  } else if (idx < 1608064) {      // bg4
    int rp = idx - 1607552;
    int y = rp >> 7, g = (rp >> 5) & 3, u = (y << 5) | (rp & 31);
    int sr = g * 128 + u;
    bg4[rp] = s2_bih2[sr] + s2_bhh2[sr];
  } else if (idx < 1608320) {      // bm2
    int i = idx - 1608064;
    bm2[i] = s2_db[i];
  }
}

// ================= input prep: LDS-tiled transpose + fused Nyquist =========
__global__ __launch_bounds__(256)
void input_prep(const float* __restrict__ x, ushort* __restrict__ XSpk,
                const float* __restrict__ st1,
                ushort* __restrict__ h1pk, ushort* __restrict__ h2pk,
                const float* __restrict__ st2,
                ushort* __restrict__ h3pk, ushort* __restrict__ h4pk,
                float* __restrict__ RI, ushort* __restrict__ magpk)
{
  __shared__ float L[16 * 516];          // x: [16][516]; state: [16][260]
  const int tid = threadIdx.x;
  const int b   = blockIdx.x;
  if (b < BN / 16) {
    const int row0 = b * 16;
    #pragma unroll
    for (int i = 0; i < 8; ++i) {        // 8192 f32, 4KB contiguous/instr
      int g = i * 1024 + tid * 4;
      int row = g >> 9, col = g & 511;
      *(float4v*)&L[row * 516 + col] = *(const float4v*)(x + (size_t)row0 * 512 + g);
    }
    __syncthreads();
    // ---- fused Nyquist: s = sum_n x[row][n] * (-1)^n ----
    if (tid < 128) {
      int row = tid >> 3, seg = tid & 7;
      const float* Lr = &L[row * 516 + seg * 64];
      float s = 0.f;
      #pragma unroll
      for (int i = 0; i < 64; i += 4) {
        float4v v4 = *(const float4v*)(Lr + i);
        s += (v4[0] - v4[1]) + (v4[2] - v4[3]);
      }
      s += __shfl_xor(s, 1, 64);
      s += __shfl_xor(s, 2, 64);
      s += __shfl_xor(s, 4, 64);
      if (seg == 0) {
        int grow = row0 + row;
        RI[(size_t)grow * 514 + 512] = s;
        RI[(size_t)grow * 514 + 513] = 0.f;
        split_pk(sqrtf(fmaxf(s * s, EPSF)), magpk, BN, grow, 256);
      }
    }
    // zero mag bins 257..287 for these rows
    #pragma unroll 1
    for (int u = tid; u < 16 * 31; u += 256) {
      int row = row0 + (u / 31), bin = 257 + (u % 31);
      magpk[pkoff(BN, row, bin, 0)] = 0;
      magpk[pkoff(BN, row, bin, 1)] = 0;
    }
    // ---- packed-layout stores (kt 0..15, vectorized LDS reads) ----
    #pragma unroll
    for (int i = 0; i < 8; ++i) {
      int u = i * 256 + tid;             // 0..2047
      int kt = u >> 7, unit = u & 127;
      int row = unit >> 3, pslot = unit & 7;
      int ls = pslot ^ (row & 7);
      const float* src = &L[row * 516 + kt * 32 + (ls & 3) * 8];
      float4v a = *(const float4v*)(src);
      float4v c = *(const float4v*)(src + 4);
      short8 out;
      if (ls < 4) {
        #pragma unroll
        for (int e = 0; e < 4; ++e) out[e]     = (short)f2b(a[e]);
        #pragma unroll
        for (int e = 0; e < 4; ++e) out[4 + e] = (short)f2b(c[e]);
      } else {
        #pragma unroll
        for (int e = 0; e < 4; ++e) {
          ushort h = f2b(a[e]);
          out[e] = (short)f2b(a[e] - b2f(h));
        }
        #pragma unroll
        for (int e = 0; e < 4; ++e) {
          ushort h = f2b(c[e]);
          out[4 + e] = (short)f2b(c[e] - b2f(h));
        }
      }
      *(short8*)(XSpk + (size_t)kt * ((size_t)BN << 6) +
                 ((size_t)(row0 + row) << 6) + pslot * 8) = out;
    }
    // chunk 16: zeros (128 units)
    if (tid < 128) {
      int row = tid >> 3, pslot = tid & 7;
      short8 z;
      #pragma unroll
      for (int e = 0; e < 8; ++e) z[e] = 0;
      *(short8*)(XSpk + (size_t)16 * ((size_t)BN << 6) +
                 ((size_t)(row0 + row) << 6) + pslot * 8) = z;
    }
  } else {
    const int lb    = b - BN / 16;
    const int layer = lb >> 10;          // BN/16 = 1024 blocks per layer
    const int row0  = (lb & 1023) * 16;
    const float* st = (layer < 2) ? st1 : st2;
    const float* sp = st + ((layer & 1) ? (size_t)BN * NH * 2 : 0) +
                      (size_t)row0 * 256;
    ushort* hp = (layer == 0) ? h1pk : (layer == 1) ? h2pk :
                 (layer == 2) ? h3pk : h4pk;
    #pragma unroll
    for (int i = 0; i < 4; ++i) {        // 4096 f32 (h,c interleaved)
      int g = i * 1024 + tid * 4;
      int row = g >> 8, col = g & 255;
      *(float4v*)&L[row * 260 + col] = *(const float4v*)(sp + g);
    }
    __syncthreads();
    #pragma unroll
    for (int it = 0; it < 2; ++it) {
      int u = it * 256 + tid;            // 0..511 = 4 chunks x 128 units
      int kt = u >> 7, unit = u & 127;
      int row = unit >> 3, pslot = unit & 7;
      int ls = pslot ^ (row & 7);
      const float* src = &L[row * 260 + (kt * 32 + (ls & 3) * 8) * 2];
      float4v v0 = *(const float4v*)(src);
      float4v v1 = *(const float4v*)(src + 4);
      float4v v2 = *(const float4v*)(src + 8);
      float4v v3 = *(const float4v*)(src + 12);
      float hvals[8] = { v0[0], v0[2], v1[0], v1[2], v2[0], v2[2], v3[0], v3[2] };
      short8 out;
      if (ls < 4) {
        #pragma unroll
        for (int e = 0; e < 8; ++e) out[e] = (short)f2b(hvals[e]);
      } else {
        #pragma unroll
        for (int e = 0; e < 8; ++e) {
          ushort h = f2b(hvals[e]);
          out[e] = (short)f2b(hvals[e] - b2f(h));
        }
      }
      *(short8*)(hp + (size_t)kt * ((size_t)BN << 6) +
                 ((size_t)(row0 + row) << 6) + pslot * 8) = out;
    }
  }
}

// LayerNorm over 256 -> packed ENCN
__global__ void ln_kernel(const float* __restrict__ ENC,
                          const float* __restrict__ gamma,
                          const float* __restrict__ beta,
                          ushort* __restrict__ opk){
  int row = blockIdx.x;
  int t = threadIdx.x;   // 64; thread handles cols 4t..4t+3
  const float* e = ENC + (size_t)row * NE;
  float v[4]; float s = 0.f;
  #pragma unroll
  for (int i = 0; i < 4; ++i) { v[i] = e[4 * t + i]; s += v[i]; }
  #pragma unroll
  for (int off = 32; off >= 1; off >>= 1) s += __shfl_xor(s, off, 64);
  float mean = s * (1.0f / NE);
  float d[4]; float ss = 0.f;
  #pragma unroll
  for (int i = 0; i < 4; ++i) { d[i] = v[i] - mean; ss += d[i] * d[i]; }
  #pragma unroll
  for (int off = 32; off >= 1; off >>= 1) ss += __shfl_xor(ss, off, 64);
  float inv = 1.0f / sqrtf(ss * (1.0f / NE) + LNEPS);
  #pragma unroll
  for (int i = 0; i < 4; ++i) {
    int col = 4 * t + i;
    float o = d[i] * inv * gamma[col] + beta[col];
    split_pk(o, opk, BN, row, col);
  }
}

// ================= launch =================
extern "C" void kernel_launch(void* const* d_in, const int* in_sizes, int n_in,
                              void* d_out, int out_size, void* d_ws, size_t ws_size,
                              hipStream_t stream)
{
  const float* x       = (const float*)d_in[0];
  const float* st1     = (const float*)d_in[1];
  const float* st2     = (const float*)d_in[2];
  const float* s1_wih1 = (const float*)d_in[3];
  const float* s1_whh1 = (const float*)d_in[4];
  const float* s1_bih1 = (const float*)d_in[5];
  const float* s1_bhh1 = (const float*)d_in[6];
  const float* s1_wih2 = (const float*)d_in[7];
  const float* s1_whh2 = (const float*)d_in[8];
  const float* s1_bih2 = (const float*)d_in[9];
  const float* s1_bhh2 = (const float*)d_in[10];
  const float* s1_dw   = (const float*)d_in[11];
  const float* s1_db   = (const float*)d_in[12];
  const float* enc_w   = (const float*)d_in[13];
  const float* ln_g    = (const float*)d_in[14];
  const float* ln_b    = (const float*)d_in[15];
  const float* s2_wih1 = (const float*)d_in[16];
  const float* s2_whh1 = (const float*)d_in[17];
  const float* s2_bih1 = (const float*)d_in[18];
  const float* s2_bhh1 = (const float*)d_in[19];
  const float* s2_wih2 = (const float*)d_in[20];
  const float* s2_whh2 = (const float*)d_in[21];
  const float* s2_bih2 = (const float*)d_in[22];
  const float* s2_bhh2 = (const float*)d_in[23];
  const float* s2_dw   = (const float*)d_in[24];
  const float* s2_db   = (const float*)d_in[25];
  const float* dec_w   = (const float*)d_in[26];

  float* out_dec = (float*)d_out;
  float* out_st1 = out_dec + (size_t)BN * NFFT;
  float* out_st2 = out_st1 + (size_t)2 * BN * NH * 2;

  // ---- workspace ----
  char* base = (char*)d_ws;
  size_t off = 0;
  auto alloc = [&](size_t bytes) -> void* {
    off = (off + 255) & ~(size_t)255;
    void* p = base + off;
    off += bytes;
    return p;
  };
  auto pkbytes = [](int rows, int nk) -> size_t {
    return (size_t)nk * rows * 64 * 2;
  };
  ushort* fwdTpk  = (ushort*)alloc(pkbytes(512, 16));
  ushort* invTtpk = (ushort*)alloc(pkbytes(640, 16));
  ushort* MEpk    = (ushort*)alloc(pkbytes(256, 20));
  ushort* XSpk    = (ushort*)alloc(pkbytes(BN, 17));
  float*  RI      = (float*) alloc((size_t)BN * 514 * 4);
  ushort* magpk   = (ushort*)alloc(pkbytes(BN, 9));
  float*  ENC     = (float*) alloc((size_t)BN * NE * 4);
  ushort* ENCNpk  = (ushort*)alloc(pkbytes(BN, 8));
  ushort* Dpk     = (ushort*)alloc(pkbytes(BN, 8));
  ushort* h1pk    = (ushort*)alloc(pkbytes(BN, 4));
  ushort* h2pk    = (ushort*)alloc(pkbytes(BN, 4));
  ushort* h3pk    = (ushort*)alloc(pkbytes(BN, 4));
  ushort* h4pk    = (ushort*)alloc(pkbytes(BN, 4));
  ushort* h1npk   = (ushort*)alloc(pkbytes(BN, 4));
  ushort* h2npk   = (ushort*)alloc(pkbytes(BN, 4));
  ushort* w11pk   = (ushort*)alloc(pkbytes(512, 9));
  ushort* wh1pk   = (ushort*)alloc(pkbytes(512, 4));
  ushort* w12pk   = (ushort*)alloc(pkbytes(512, 4));
  ushort* wh2pk   = (ushort*)alloc(pkbytes(512, 4));
  ushort* dw1pk   = (ushort*)alloc(pkbytes(384, 4));
  ushort* encwpk  = (ushort*)alloc(pkbytes(256, 16));
  ushort* w21pk   = (ushort*)alloc(pkbytes(512, 8));
  ushort* wh3pk   = (ushort*)alloc(pkbytes(512, 4));
  ushort* w22pk   = (ushort*)alloc(pkbytes(512, 4));
  ushort* wh4pk   = (ushort*)alloc(pkbytes(512, 4));
  ushort* dw2pk   = (ushort*)alloc(pkbytes(256, 4));
  ushort* decwpk  = (ushort*)alloc(pkbytes(512, 8));
  float* bg1 = (float*)alloc(512*4); float* bg2 = (float*)alloc(512*4);
  float* bm1 = (float*)alloc(384*4);
  float* bg3 = (float*)alloc(512*4); float* bg4 = (float*)alloc(512*4);
  float* bm2 = (float*)alloc(256*4);
  (void)ws_size; (void)in_sizes; (void)n_in; (void)out_size;

  const dim3 blk(256);

  // ---- one consolidated prep launch (twiddles + weights + biases) ----
  prep_all<<<(1608320 + 255) / 256, blk, 0, stream>>>(
      s1_wih1, s1_whh1, s1_wih2, s1_whh2, s1_dw, enc_w,
      s2_wih1, s2_whh1, s2_wih2, s2_whh2, s2_dw, dec_w,
      s1_bih1, s1_bhh1, s1_bih2, s1_bhh2, s1_db,
      s2_bih1, s2_bhh1, s2_bih2, s2_bhh2, s2_db,
      fwdTpk, invTtpk,
      w11pk, wh1pk, w12pk, wh2pk, dw1pk, encwpk, w21pk, wh3pk,
      w22pk, wh4pk, dw2pk, decwpk,
      bg1, bg2, bm1, bg3, bg4, bm2);

  // ---- ME = enc_w x invT (256x640, K=512) -> packed (folds irfft into enc) ----
  mfma_gemm<M_PLANES><<<dim3(2,5), blk, 0, stream>>>(encwpk, 256, 16, invTtpk, 640,
      nullptr, 0, nullptr, 0,
      nullptr, nullptr, 256, nullptr, nullptr, nullptr, MEpk);

  // ---- one consolidated input prep (LDS transpose + fused Nyquist) ----
  input_prep<<<BN / 16 + 4 * (BN / 16), blk, 0, stream>>>(
      x, XSpk, st1, h1pk, h2pk, st2, h3pk, h4pk, RI, magpk);

  // ---- rfft (+fused magphase) ----
  mfma_gemm<M_RFFT><<<dim3(128,4), blk, 0, stream>>>(XSpk, BN, 16, fwdTpk, 512,
      nullptr, 0, nullptr, 0,
      nullptr, RI, 514, nullptr, nullptr, nullptr, magpk);

  // ---- sep block 1 (fused LSTM epilogues; c read from st directly) ----
  mfma_gemm<M_LSTM><<<dim3(128,4), blk, 0, stream>>>(magpk, BN, 9, w11pk, 512,
      h1pk, 4, wh1pk, 512,
      bg1, nullptr, 0, st1, nullptr, out_st1, h1npk);
  mfma_gemm<M_LSTM><<<dim3(128,4), blk, 0, stream>>>(h1npk, BN, 4, w12pk, 512,
      h2pk, 4, wh2pk, 512,
      bg2, nullptr, 0, st1 + (size_t)BN*NH*2, nullptr,
      out_st1 + (size_t)BN*NH*2, h2npk);
  // ---- mask1 + fused est_build -> XS packed ----
  mfma_gemm<M_EST><<<dim3(128,3), blk, 0, stream>>>(h2npk, BN, 4, dw1pk, 384,
      nullptr, 0, nullptr, 0,
      bm1, nullptr, 0, RI, magpk, nullptr, XSpk);

  // ---- encoder (irfft folded via ME) + LN ----
  mfma_gemm<M_F32><<<dim3(128,2), blk, 0, stream>>>(XSpk, BN, 17, MEpk, 256,
      nullptr, 0, nullptr, 0,
      nullptr, ENC, 256, nullptr, nullptr, nullptr, nullptr);
  ln_kernel<<<BN, 64, 0, stream>>>(ENC, ln_g, ln_b, ENCNpk);

  // ---- sep block 2 ----
  mfma_gemm<M_LSTM><<<dim3(128,4), blk, 0, stream>>>(ENCNpk, BN, 8, w21pk, 512,
      h3pk, 4, wh3pk, 512,
      bg3, nullptr, 0, st2, nullptr, out_st2, h1npk);
  mfma_gemm<M_LSTM><<<dim3(128,4), blk, 0, stream>>>(h1npk, BN, 4, w22pk, 512,
      h4pk, 4, wh4pk, 512,
      bg4, nullptr, 0, st2 + (size_t)BN*NH*2, nullptr,
      out_st2 + (size_t)BN*NH*2, h2npk);
  // ---- mask2 + fused dec_in -> D packed ----
  mfma_gemm<M_DEC><<<dim3(128,2), blk, 0, stream>>>(h2npk, BN, 4, dw2pk, 256,
      nullptr, 0, nullptr, 0,
      bm2, nullptr, 0, ENC, nullptr, nullptr, Dpk);

  // ---- decoder ----
  mfma_gemm<M_F32><<<dim3(128,4), blk, 0, stream>>>(Dpk, BN, 8, decwpk, 512,
      nullptr, 0, nullptr, 0,
      nullptr, out_dec, 512, nullptr, nullptr, nullptr, nullptr);
}

// Round 19
// 314.495 us; speedup vs baseline: 1.2293x; 1.2030x over previous
//
#include <hip/hip_runtime.h>
#include <hip/hip_bf16.h>
#include <math.h>

static constexpr int BN   = 16384;
static constexpr int NFFT = 512;
static constexpr int NBIN = 257;
static constexpr int NH   = 128;
static constexpr int NE   = 256;
static constexpr float EPSF  = 1.1920929e-07f;
static constexpr float LNEPS = 1e-07f;

using short8  = __attribute__((ext_vector_type(8))) short;
using float4v = __attribute__((ext_vector_type(4))) float;

__device__ __forceinline__ float sigm(float x){ return 1.0f/(1.0f+expf(-x)); }
__device__ __forceinline__ ushort f2b(float v){
  __hip_bfloat16 b = __float2bfloat16(v);
  return *reinterpret_cast<ushort*>(&b);
}
__device__ __forceinline__ float b2f(ushort u){
  __hip_bfloat16 b = *reinterpret_cast<__hip_bfloat16*>(&u);
  return __bfloat162float(b);
}

// ---- packed staging-ready layout ----
// matrix [rows][K] stored as chunks: chunk kt (32 k) x row -> 128B:
// 8 slots x 16B; slot p at row r holds LOGICAL slot p^(r&7);
// logical slots 0..3 = hi bf16 of k sub-chunks, 4..7 = lo bf16.
__device__ __forceinline__ size_t pkoff(int rows, int row, int k, int lo){
  const int ls = ((((k >> 3) & 3) | (lo << 2)) ^ (row & 7));
  return (size_t)(k >> 5) * ((size_t)rows << 6) + ((size_t)row << 6) + (ls << 3) + (k & 7);
}
__device__ __forceinline__ void split_pk(float v, ushort* base, int rows, int row, int k){
  ushort h = f2b(v);
  base[pkoff(rows, row, k, 0)] = h;
  base[pkoff(rows, row, k, 1)] = f2b(v - b2f(h));
}
__device__ __forceinline__ float read_pk(const ushort* base, int rows, int row, int k){
  return b2f(base[pkoff(rows, row, k, 0)]) + b2f(base[pkoff(rows, row, k, 1)]);
}

__device__ __forceinline__ void gload16(const ushort* g, ushort* l){
  __builtin_amdgcn_global_load_lds(
      (const __attribute__((address_space(1))) unsigned int*)g,
      (__attribute__((address_space(3))) unsigned int*)l,
      16, 0, 0);
}

// epilogue modes
enum { M_F32 = 0, M_PLANES = 1, M_LSTM = 2, M_EST = 3, M_DEC = 4, M_RFFT = 5 };

// ================= MFMA bf16x2 NT GEMM, BM=64 / BN=128, packed operands ====
// (R7 structure: BK=32, single-buffered 24KB LDS, 4 blocks/CU at grid 1024)
// C[row][col] = sum_k A[row][k]*B[col][k] (+ optional phase2 A2/B2)
// MODE_LSTM expects gate-PERMUTED weights/bias: col' = 128*(u>>5)+32*g+(u&31).
// M_LSTM: aux0 = ORIGINAL state buffer (h,c interleaved); c = aux0[2*idx+1].
template<int MODE>
__global__ __launch_bounds__(256)
void mfma_gemm(const ushort* __restrict__ Apk, int MA, int nkA,
               const ushort* __restrict__ Bpk, int MB,
               const ushort* __restrict__ A2pk, int nkA2,
               const ushort* __restrict__ B2pk, int MB2,
               const float* __restrict__ bias,
               float* __restrict__ C, int ldc,
               const float* __restrict__ aux0,   // LSTM: st base | EST: RI | DEC: ENC
               const ushort* __restrict__ auxpk, // EST: mag packed
               float* __restrict__ out0,         // LSTM: out_state (h,c pairs)
               ushort* __restrict__ opk)         // packed output
{
  constexpr int LDSW = (MODE == M_LSTM) ? 16384 : 12288;
  __shared__ ushort smem[LDSW];
  const int tid  = threadIdx.x;
  const int row0 = blockIdx.x * 64;
  const int col0 = blockIdx.y * 128;
  const int lane = tid & 63;
  const int wv   = tid >> 6;
  const int wr   = (wv >> 1) * 32;   // 0 / 32
  const int wc   = (wv & 1) * 64;    // 0 / 64
  const int fr   = lane & 15;
  const int quad = lane >> 4;

  float4v acc[2][4];
  #pragma unroll
  for (int i = 0; i < 2; ++i)
    #pragma unroll
    for (int j = 0; j < 4; ++j)
      acc[i][j] = float4v{0.f, 0.f, 0.f, 0.f};

  const int nt0 = nkA;
  const int nt1 = A2pk ? nkA2 : 0;
  const int nt  = nt0 + nt1;

  const size_t astr  = (size_t)MA << 6;
  const size_t bstr  = (size_t)MB << 6;
  const size_t bstr2 = (size_t)MB2 << 6;
  size_t abase[2], bbase[4];
  #pragma unroll
  for (int s = 0; s < 2; ++s)
    abase[s] = ((size_t)(row0 + (wv * 2 + s) * 8) << 6) + lane * 8;
  #pragma unroll
  for (int s = 0; s < 4; ++s)
    bbase[s] = ((size_t)(col0 + (wv * 4 + s) * 8) << 6) + lane * 8;

  #pragma unroll 1
  for (int t = 0; t < nt; ++t) {
    // ---- stage: each instruction = 1KB contiguous ----
    if (t < nt0) {
      #pragma unroll
      for (int s = 0; s < 2; ++s)
        gload16(Apk + (size_t)t * astr + abase[s], &smem[(wv * 2 + s) * 512]);
      #pragma unroll
      for (int s = 0; s < 4; ++s)
        gload16(Bpk + (size_t)t * bstr + bbase[s], &smem[4096 + (wv * 4 + s) * 512]);
    } else {
      const size_t kt = t - nt0;
      #pragma unroll
      for (int s = 0; s < 2; ++s)
        gload16(A2pk + kt * astr + abase[s], &smem[(wv * 2 + s) * 512]);
      #pragma unroll
      for (int s = 0; s < 4; ++s)
        gload16(B2pk + kt * bstr2 + bbase[s], &smem[4096 + (wv * 4 + s) * 512]);
    }
    asm volatile("s_waitcnt vmcnt(0)" ::: "memory");
    __syncthreads();

    // ---- fragments (swizzled reads) ----
    const char* Ab = (const char*)smem;
    const char* Bb = (const char*)(smem + 4096);
    short8 ah[2], al[2], bh[4], bl[4];
    #pragma unroll
    for (int i = 0; i < 2; ++i) {
      const int ra  = wr + i * 16 + fr;
      const int swa = (ra & 7) << 4;
      ah[i] = *(const short8*)(Ab + ra * 128 + ((quad << 4) ^ swa));
      al[i] = *(const short8*)(Ab + ra * 128 + ((64 | (quad << 4)) ^ swa));
    }
    #pragma unroll
    for (int j = 0; j < 4; ++j) {
      const int rb  = wc + j * 16 + fr;
      const int swb = (rb & 7) << 4;
      bh[j] = *(const short8*)(Bb + rb * 128 + ((quad << 4) ^ swb));
      bl[j] = *(const short8*)(Bb + rb * 128 + ((64 | (quad << 4)) ^ swb));
    }
    #pragma unroll
    for (int i = 0; i < 2; ++i)
      #pragma unroll
      for (int j = 0; j < 4; ++j) {
        acc[i][j] = __builtin_amdgcn_mfma_f32_16x16x32_bf16(ah[i], bh[j], acc[i][j], 0, 0, 0);
        acc[i][j] = __builtin_amdgcn_mfma_f32_16x16x32_bf16(ah[i], bl[j], acc[i][j], 0, 0, 0);
        acc[i][j] = __builtin_amdgcn_mfma_f32_16x16x32_bf16(al[i], bh[j], acc[i][j], 0, 0, 0);
      }
    __syncthreads();
  }

  // ---- epilogues; C/D layout: col=lane&15 group, row=quad*4+reg ----
  if constexpr (MODE == M_F32) {
    #pragma unroll
    for (int j = 0; j < 4; ++j) {
      const int colb = col0 + wc + j * 16 + fr;
      const float bv = bias ? bias[colb] : 0.f;
      #pragma unroll
      for (int i = 0; i < 2; ++i)
        #pragma unroll
        for (int r = 0; r < 4; ++r) {
          const int row = row0 + wr + i * 16 + quad * 4 + r;
          C[(size_t)row * ldc + colb] = acc[i][j][r] + bv;
        }
    }
  } else if constexpr (MODE == M_PLANES) {
    #pragma unroll
    for (int j = 0; j < 4; ++j) {
      const int colb = col0 + wc + j * 16 + fr;
      #pragma unroll
      for (int i = 0; i < 2; ++i)
        #pragma unroll
        for (int r = 0; r < 4; ++r) {
          const int row = row0 + wr + i * 16 + quad * 4 + r;
          split_pk(acc[i][j][r], opk, ldc, row, colb);   // ldc = rows of output
        }
    }
  } else if constexpr (MODE == M_RFFT) {
    #pragma unroll
    for (int j = 0; j < 4; ++j) {
      const int colb = col0 + wc + j * 16 + fr;
      #pragma unroll
      for (int i = 0; i < 2; ++i)
        #pragma unroll
        for (int r = 0; r < 4; ++r) {
          const int row = row0 + wr + i * 16 + quad * 4 + r;
          const float v = acc[i][j][r];
          C[(size_t)row * ldc + colb] = v;
          const float w = __shfl_xor(v, 1, 64);
          if (!(lane & 1)) {
            const int bin = colb >> 1;
            const float mg = sqrtf(fmaxf(v * v + w * w, EPSF));
            split_pk(mg, opk, BN, row, bin);
          }
        }
    }
  } else if constexpr (MODE == M_EST) {
    #pragma unroll
    for (int j = 0; j < 4; ++j) {
      const int colg = col0 + wc + j * 16 + fr;   // bin index
      const float bv = bias[colg];
      #pragma unroll
      for (int i = 0; i < 2; ++i)
        #pragma unroll
        for (int r = 0; r < 4; ++r) {
          const int row = row0 + wr + i * 16 + quad * 4 + r;
          if (colg < NBIN) {
            const float m   = sigm(acc[i][j][r] + bv);
            const float mag = read_pk(auxpk, BN, row, colg);
            const float e   = m * mag;
            const float rr  = aux0[(size_t)row * 514 + 2 * colg];
            const float im  = aux0[(size_t)row * 514 + 2 * colg + 1];
            const float re = rr + EPSF, ie = im + EPSF;
            const float hyp = fmaxf(sqrtf(re * re + ie * ie), 1e-35f);
            split_pk(e * re / hyp, opk, BN, row, 2 * colg);
            split_pk(e * ie / hyp, opk, BN, row, 2 * colg + 1);
          } else if (colg < 272) {
            const int k0 = 2 * colg;
            opk[pkoff(BN, row, k0, 0)] = 0;     opk[pkoff(BN, row, k0, 1)] = 0;
            opk[pkoff(BN, row, k0 + 1, 0)] = 0; opk[pkoff(BN, row, k0 + 1, 1)] = 0;
          }
        }
    }
  } else if constexpr (MODE == M_DEC) {
    #pragma unroll
    for (int j = 0; j < 4; ++j) {
      const int colg = col0 + wc + j * 16 + fr;
      const float bv = bias[colg];
      #pragma unroll
      for (int i = 0; i < 2; ++i)
        #pragma unroll
        for (int r = 0; r < 4; ++r) {
          const int row = row0 + wr + i * 16 + quad * 4 + r;
          const float v = sigm(acc[i][j][r] + bv) * aux0[(size_t)row * NE + colg];
          split_pk(v, opk, BN, row, colg);
        }
    }
  } else {
    // M_LSTM: block's 128 cols = units ub..ub+31, gates 0..3 (permuted)
    float* Ep = (float*)smem;   // 64 rows x 128 gate-cols f32 = 32 KB
    const int ub = blockIdx.y << 5;
    #pragma unroll
    for (int j = 0; j < 4; ++j) {
      const int cl = wc + j * 16 + fr;
      const float bv = bias[col0 + cl];
      #pragma unroll
      for (int i = 0; i < 2; ++i)
        #pragma unroll
        for (int r = 0; r < 4; ++r)
          Ep[(wr + i * 16 + quad * 4 + r) * 128 + cl] = acc[i][j][r] + bv;
    }
    __syncthreads();
    #pragma unroll
    for (int k = 0; k < 8; ++k) {
      const int cell = tid + 256 * k;        // 0..2047
      const int ul = cell & 31;
      const int er = cell >> 5;              // 0..63
      const int row = row0 + er;
      const int unit = ub + ul;
      const float gi = Ep[er * 128 + ul];
      const float gf = Ep[er * 128 + 32 + ul];
      const float gc = Ep[er * 128 + 64 + ul];
      const float go = Ep[er * 128 + 96 + ul];
      const size_t sidx = (size_t)row * NH + unit;
      const float cp = aux0[2 * sidx + 1];           // c from original state
      const float cn = sigm(gf) * cp + sigm(gi) * tanhf(gc);
      const float hn = sigm(go) * tanhf(cn);
      split_pk(hn, opk, BN, row, unit);
      float2 hc; hc.x = hn; hc.y = cn;
      *(float2*)(out0 + 2 * sidx) = hc;
    }
  }
}

// ================= consolidated prep: twiddles + weights + biases ==========
__device__ __forceinline__ void do_wconv_pk(const float* src, int M0, int K0,
                                            ushort* dst, int Mp, int Kp, int li){
  int r = li / Kp, k = li - r * Kp;
  float v = (r < M0 && k < K0) ? src[(size_t)r * K0 + k] : 0.f;
  split_pk(v, dst, Mp, r, k);
}
__device__ __forceinline__ void do_wconv_g_pk(const float* src, int K0,
                                              ushort* dst, int Kp, int li){
  int rp = li / Kp, k = li - rp * Kp;
  int y = rp >> 7, g = (rp >> 5) & 3, u = (y << 5) | (rp & 31);
  float v = (k < K0) ? src[(size_t)(g * 128 + u) * K0 + k] : 0.f;
  split_pk(v, dst, 512, rp, k);
}

__global__ void prep_all(
    const float* s1_wih1, const float* s1_whh1, const float* s1_wih2,
    const float* s1_whh2, const float* s1_dw,   const float* enc_w,
    const float* s2_wih1, const float* s2_whh1, const float* s2_wih2,
    const float* s2_whh2, const float* s2_dw,   const float* dec_w,
    const float* s1_bih1, const float* s1_bhh1, const float* s1_bih2,
    const float* s1_bhh2, const float* s1_db,
    const float* s2_bih1, const float* s2_bhh1, const float* s2_bih2,
    const float* s2_bhh2, const float* s2_db,
    ushort* fwdTpk, ushort* invTtpk,
    ushort* w11pk, ushort* wh1pk, ushort* w12pk, ushort* wh2pk,
    ushort* dw1pk, ushort* encwpk, ushort* w21pk, ushort* wh3pk,
    ushort* w22pk, ushort* wh4pk, ushort* dw2pk, ushort* decwpk,
    float* bg1, float* bg2, float* bm1, float* bg3, float* bg4, float* bm2)
{
  int idx = blockIdx.x * blockDim.x + threadIdx.x;
  if (idx < 262144) {              // fwdT [512 c][512 n]
    int c = idx >> 9, n = idx & 511;
    int k = c >> 1, m = (k * n) & 511;
    float th = (float)m * (6.283185307179586f / 512.0f);
    float s, co; sincosf(th, &s, &co);
    split_pk((c & 1) ? -s : co, fwdTpk, 512, c, n);
  } else if (idx < 589824) {       // invT^T [640 c][512 n]
    int li = idx - 262144;
    int c = li >> 9, n = li & 511;
    float v = 0.f;
    if (c < 512) {
      int k = c >> 1, m = (k * n) & 511;
      float th = (float)m * (6.283185307179586f / 512.0f);
      float s, co; sincosf(th, &s, &co);
      float w = (k == 0) ? (1.0f / 512.0f) : (2.0f / 512.0f);
      v = (c & 1) ? -w * s : w * co;
    } else if (c == 512) {
      v = ((n & 1) ? -1.0f : 1.0f) / 512.0f;
    }
    split_pk(v, invTtpk, 640, c, n);
  } else if (idx < 737280)  { do_wconv_g_pk(s1_wih1, 257, w11pk, 288, idx - 589824);
  } else if (idx < 802816)  { do_wconv_g_pk(s1_whh1, 128, wh1pk, 128, idx - 737280);
  } else if (idx < 868352)  { do_wconv_g_pk(s1_wih2, 128, w12pk, 128, idx - 802816);
  } else if (idx < 933888)  { do_wconv_g_pk(s1_whh2, 128, wh2pk, 128, idx - 868352);
  } else if (idx < 983040)  { do_wconv_pk(s1_dw, 257, 128, dw1pk, 384, 128, idx - 933888);
  } else if (idx < 1114112) { do_wconv_pk(enc_w, 256, 512, encwpk, 256, 512, idx - 983040);
  } else if (idx < 1245184) { do_wconv_g_pk(s2_wih1, 256, w21pk, 256, idx - 1114112);
  } else if (idx < 1310720) { do_wconv_g_pk(s2_whh1, 128, wh3pk, 128, idx - 1245184);
  } else if (idx < 1376256) { do_wconv_g_pk(s2_wih2, 128, w22pk, 128, idx - 1310720);
  } else if (idx < 1441792) { do_wconv_g_pk(s2_whh2, 128, wh4pk, 128, idx - 1376256);
  } else if (idx < 1474560) { do_wconv_pk(s2_dw, 256, 128, dw2pk, 256, 128, idx - 1441792);
  } else if (idx < 1605632) { do_wconv_pk(dec_w, 512, 256, decwpk, 512, 256, idx - 1474560);
  } else if (idx < 1606144) {      // bg1
    int rp = idx - 1605632;
    int y = rp >> 7, g = (rp >> 5) & 3, u = (y << 5) | (rp & 31);
    int sr = g * 128 + u;
    bg1[rp] = s1_bih1[sr] + s1_bhh1[sr];
  } else if (idx < 1606656) {      // bg2
    int rp = idx - 1606144;
    int y = rp >> 7, g = (rp >> 5) & 3, u = (y << 5) | (rp & 31);
    int sr = g * 128 + u;
    bg2[rp] = s1_bih2[sr] + s1_bhh2[sr];
  } else if (idx < 1607040) {      // bm1 (pad 257 -> 384)
    int i = idx - 1606656;
    bm1[i] = (i < 257) ? s1_db[i] : 0.f;
  } else if (idx < 1607552) {      // bg3
    int rp = idx - 1607040;
    int y = rp >> 7, g = (rp >> 5) & 3, u = (y << 5) | (rp & 31);
    int sr = g * 128 + u;
    bg3[rp] = s2_bih1[sr] + s2_bhh1[sr];
  } else if (idx < 1608064) {      // bg4
    int rp = idx - 1607552;
    int y = rp >> 7, g = (rp >> 5) & 3, u = (y << 5) | (rp & 31);
    int sr = g * 128 + u;
    bg4[rp] = s2_bih2[sr] + s2_bhh2[sr];
  } else if (idx < 1608320) {      // bm2
    int i = idx - 1608064;
    bm2[i] = s2_db[i];
  }
}

// ================= input prep: LDS-tiled transpose + fused Nyquist =========
__global__ __launch_bounds__(256)
void input_prep(const float* __restrict__ x, ushort* __restrict__ XSpk,
                const float* __restrict__ st1,
                ushort* __restrict__ h1pk, ushort* __restrict__ h2pk,
                const float* __restrict__ st2,
                ushort* __restrict__ h3pk, ushort* __restrict__ h4pk,
                float* __restrict__ RI, ushort* __restrict__ magpk)
{
  __shared__ float L[16 * 516];          // x: [16][516]; state: [16][260]
  const int tid = threadIdx.x;
  const int b   = blockIdx.x;
  if (b < BN / 16) {
    const int row0 = b * 16;
    #pragma unroll
    for (int i = 0; i < 8; ++i) {        // 8192 f32, 4KB contiguous/instr
      int g = i * 1024 + tid * 4;
      int row = g >> 9, col = g & 511;
      *(float4v*)&L[row * 516 + col] = *(const float4v*)(x + (size_t)row0 * 512 + g);
    }
    __syncthreads();
    // ---- fused Nyquist: s = sum_n x[row][n] * (-1)^n ----
    if (tid < 128) {
      int row = tid >> 3, seg = tid & 7;
      const float* Lr = &L[row * 516 + seg * 64];
      float s = 0.f;
      #pragma unroll
      for (int i = 0; i < 64; i += 4) {
        float4v v4 = *(const float4v*)(Lr + i);
        s += (v4[0] - v4[1]) + (v4[2] - v4[3]);
      }
      s += __shfl_xor(s, 1, 64);
      s += __shfl_xor(s, 2, 64);
      s += __shfl_xor(s, 4, 64);
      if (seg == 0) {
        int grow = row0 + row;
        RI[(size_t)grow * 514 + 512] = s;
        RI[(size_t)grow * 514 + 513] = 0.f;
        split_pk(sqrtf(fmaxf(s * s, EPSF)), magpk, BN, grow, 256);
      }
    }
    // zero mag bins 257..287 for these rows
    #pragma unroll 1
    for (int u = tid; u < 16 * 31; u += 256) {
      int row = row0 + (u / 31), bin = 257 + (u % 31);
      magpk[pkoff(BN, row, bin, 0)] = 0;
      magpk[pkoff(BN, row, bin, 1)] = 0;
    }
    // ---- packed-layout stores (kt 0..15, vectorized LDS reads) ----
    #pragma unroll
    for (int i = 0; i < 8; ++i) {
      int u = i * 256 + tid;             // 0..2047
      int kt = u >> 7, unit = u & 127;
      int row = unit >> 3, pslot = unit & 7;
      int ls = pslot ^ (row & 7);
      const float* src = &L[row * 516 + kt * 32 + (ls & 3) * 8];
      float4v a = *(const float4v*)(src);
      float4v c = *(const float4v*)(src + 4);
      short8 out;
      if (ls < 4) {
        #pragma unroll
        for (int e = 0; e < 4; ++e) out[e]     = (short)f2b(a[e]);
        #pragma unroll
        for (int e = 0; e < 4; ++e) out[4 + e] = (short)f2b(c[e]);
      } else {
        #pragma unroll
        for (int e = 0; e < 4; ++e) {
          ushort h = f2b(a[e]);
          out[e] = (short)f2b(a[e] - b2f(h));
        }
        #pragma unroll
        for (int e = 0; e < 4; ++e) {
          ushort h = f2b(c[e]);
          out[4 + e] = (short)f2b(c[e] - b2f(h));
        }
      }
      *(short8*)(XSpk + (size_t)kt * ((size_t)BN << 6) +
                 ((size_t)(row0 + row) << 6) + pslot * 8) = out;
    }
    // chunk 16: zeros (128 units)
    if (tid < 128) {
      int row = tid >> 3, pslot = tid & 7;
      short8 z;
      #pragma unroll
      for (int e = 0; e < 8; ++e) z[e] = 0;
      *(short8*)(XSpk + (size_t)16 * ((size_t)BN << 6) +
                 ((size_t)(row0 + row) << 6) + pslot * 8) = z;
    }
  } else {
    const int lb    = b - BN / 16;
    const int layer = lb >> 10;          // BN/16 = 1024 blocks per layer
    const int row0  = (lb & 1023) * 16;
    const float* st = (layer < 2) ? st1 : st2;
    const float* sp = st + ((layer & 1) ? (size_t)BN * NH * 2 : 0) +
                      (size_t)row0 * 256;
    ushort* hp = (layer == 0) ? h1pk : (layer == 1) ? h2pk :
                 (layer == 2) ? h3pk : h4pk;
    #pragma unroll
    for (int i = 0; i < 4; ++i) {        // 4096 f32 (h,c interleaved)
      int g = i * 1024 + tid * 4;
      int row = g >> 8, col = g & 255;
      *(float4v*)&L[row * 260 + col] = *(const float4v*)(sp + g);
    }
    __syncthreads();
    #pragma unroll
    for (int it = 0; it < 2; ++it) {
      int u = it * 256 + tid;            // 0..511 = 4 chunks x 128 units
      int kt = u >> 7, unit = u & 127;
      int row = unit >> 3, pslot = unit & 7;
      int ls = pslot ^ (row & 7);
      const float* src = &L[row * 260 + (kt * 32 + (ls & 3) * 8) * 2];
      float4v v0 = *(const float4v*)(src);
      float4v v1 = *(const float4v*)(src + 4);
      float4v v2 = *(const float4v*)(src + 8);
      float4v v3 = *(const float4v*)(src + 12);
      float hvals[8] = { v0[0], v0[2], v1[0], v1[2], v2[0], v2[2], v3[0], v3[2] };
      short8 out;
      if (ls < 4) {
        #pragma unroll
        for (int e = 0; e < 8; ++e) out[e] = (short)f2b(hvals[e]);
      } else {
        #pragma unroll
        for (int e = 0; e < 8; ++e) {
          ushort h = f2b(hvals[e]);
          out[e] = (short)f2b(hvals[e] - b2f(h));
        }
      }
      *(short8*)(hp + (size_t)kt * ((size_t)BN << 6) +
                 ((size_t)(row0 + row) << 6) + pslot * 8) = out;
    }
  }
}

// LayerNorm over 256 -> packed ENCN
__global__ void ln_kernel(const float* __restrict__ ENC,
                          const float* __restrict__ gamma,
                          const float* __restrict__ beta,
                          ushort* __restrict__ opk){
  int row = blockIdx.x;
  int t = threadIdx.x;   // 64; thread handles cols 4t..4t+3
  const float* e = ENC + (size_t)row * NE;
  float v[4]; float s = 0.f;
  #pragma unroll
  for (int i = 0; i < 4; ++i) { v[i] = e[4 * t + i]; s += v[i]; }
  #pragma unroll
  for (int off = 32; off >= 1; off >>= 1) s += __shfl_xor(s, off, 64);
  float mean = s * (1.0f / NE);
  float d[4]; float ss = 0.f;
  #pragma unroll
  for (int i = 0; i < 4; ++i) { d[i] = v[i] - mean; ss += d[i] * d[i]; }
  #pragma unroll
  for (int off = 32; off >= 1; off >>= 1) ss += __shfl_xor(ss, off, 64);
  float inv = 1.0f / sqrtf(ss * (1.0f / NE) + LNEPS);
  #pragma unroll
  for (int i = 0; i < 4; ++i) {
    int col = 4 * t + i;
    float o = d[i] * inv * gamma[col] + beta[col];
    split_pk(o, opk, BN, row, col);
  }
}

// ================= launch =================
extern "C" void kernel_launch(void* const* d_in, const int* in_sizes, int n_in,
                              void* d_out, int out_size, void* d_ws, size_t ws_size,
                              hipStream_t stream)
{
  const float* x       = (const float*)d_in[0];
  const float* st1     = (const float*)d_in[1];
  const float* st2     = (const float*)d_in[2];
  const float* s1_wih1 = (const float*)d_in[3];
  const float* s1_whh1 = (const float*)d_in[4];
  const float* s1_bih1 = (const float*)d_in[5];
  const float* s1_bhh1 = (const float*)d_in[6];
  const float* s1_wih2 = (const float*)d_in[7];
  const float* s1_whh2 = (const float*)d_in[8];
  const float* s1_bih2 = (const float*)d_in[9];
  const float* s1_bhh2 = (const float*)d_in[10];
  const float* s1_dw   = (const float*)d_in[11];
  const float* s1_db   = (const float*)d_in[12];
  const float* enc_w   = (const float*)d_in[13];
  const float* ln_g    = (const float*)d_in[14];
  const float* ln_b    = (const float*)d_in[15];
  const float* s2_wih1 = (const float*)d_in[16];
  const float* s2_whh1 = (const float*)d_in[17];
  const float* s2_bih1 = (const float*)d_in[18];
  const float* s2_bhh1 = (const float*)d_in[19];
  const float* s2_wih2 = (const float*)d_in[20];
  const float* s2_whh2 = (const float*)d_in[21];
  const float* s2_bih2 = (const float*)d_in[22];
  const float* s2_bhh2 = (const float*)d_in[23];
  const float* s2_dw   = (const float*)d_in[24];
  const float* s2_db   = (const float*)d_in[25];
  const float* dec_w   = (const float*)d_in[26];

  float* out_dec = (float*)d_out;
  float* out_st1 = out_dec + (size_t)BN * NFFT;
  float* out_st2 = out_st1 + (size_t)2 * BN * NH * 2;

  // ---- workspace ----
  char* base = (char*)d_ws;
  size_t off = 0;
  auto alloc = [&](size_t bytes) -> void* {
    off = (off + 255) & ~(size_t)255;
    void* p = base + off;
    off += bytes;
    return p;
  };
  auto pkbytes = [](int rows, int nk) -> size_t {
    return (size_t)nk * rows * 64 * 2;
  };
  ushort* fwdTpk  = (ushort*)alloc(pkbytes(512, 16));
  ushort* invTtpk = (ushort*)alloc(pkbytes(640, 16));
  ushort* MEpk    = (ushort*)alloc(pkbytes(256, 20));
  ushort* XSpk    = (ushort*)alloc(pkbytes(BN, 17));
  float*  RI      = (float*) alloc((size_t)BN * 514 * 4);
  ushort* magpk   = (ushort*)alloc(pkbytes(BN, 9));
  float*  ENC     = (float*) alloc((size_t)BN * NE * 4);
  ushort* ENCNpk  = (ushort*)alloc(pkbytes(BN, 8));
  ushort* Dpk     = (ushort*)alloc(pkbytes(BN, 8));
  ushort* h1pk    = (ushort*)alloc(pkbytes(BN, 4));
  ushort* h2pk    = (ushort*)alloc(pkbytes(BN, 4));
  ushort* h3pk    = (ushort*)alloc(pkbytes(BN, 4));
  ushort* h4pk    = (ushort*)alloc(pkbytes(BN, 4));
  ushort* h1npk   = (ushort*)alloc(pkbytes(BN, 4));
  ushort* h2npk   = (ushort*)alloc(pkbytes(BN, 4));
  ushort* w11pk   = (ushort*)alloc(pkbytes(512, 9));
  ushort* wh1pk   = (ushort*)alloc(pkbytes(512, 4));
  ushort* w12pk   = (ushort*)alloc(pkbytes(512, 4));
  ushort* wh2pk   = (ushort*)alloc(pkbytes(512, 4));
  ushort* dw1pk   = (ushort*)alloc(pkbytes(384, 4));
  ushort* encwpk  = (ushort*)alloc(pkbytes(256, 16));
  ushort* w21pk   = (ushort*)alloc(pkbytes(512, 8));
  ushort* wh3pk   = (ushort*)alloc(pkbytes(512, 4));
  ushort* w22pk   = (ushort*)alloc(pkbytes(512, 4));
  ushort* wh4pk   = (ushort*)alloc(pkbytes(512, 4));
  ushort* dw2pk   = (ushort*)alloc(pkbytes(256, 4));
  ushort* decwpk  = (ushort*)alloc(pkbytes(512, 8));
  float* bg1 = (float*)alloc(512*4); float* bg2 = (float*)alloc(512*4);
  float* bm1 = (float*)alloc(384*4);
  float* bg3 = (float*)alloc(512*4); float* bg4 = (float*)alloc(512*4);
  float* bm2 = (float*)alloc(256*4);
  (void)ws_size; (void)in_sizes; (void)n_in; (void)out_size;

  const dim3 blk(256);

  // ---- one consolidated prep launch (twiddles + weights + biases) ----
  prep_all<<<(1608320 + 255) / 256, blk, 0, stream>>>(
      s1_wih1, s1_whh1, s1_wih2, s1_whh2, s1_dw, enc_w,
      s2_wih1, s2_whh1, s2_wih2, s2_whh2, s2_dw, dec_w,
      s1_bih1, s1_bhh1, s1_bih2, s1_bhh2, s1_db,
      s2_bih1, s2_bhh1, s2_bih2, s2_bhh2, s2_db,
      fwdTpk, invTtpk,
      w11pk, wh1pk, w12pk, wh2pk, dw1pk, encwpk, w21pk, wh3pk,
      w22pk, wh4pk, dw2pk, decwpk,
      bg1, bg2, bm1, bg3, bg4, bm2);

  // ---- ME = enc_w x invT (256x640, K=512) -> packed (folds irfft into enc) ----
  mfma_gemm<M_PLANES><<<dim3(4,5), blk, 0, stream>>>(encwpk, 256, 16, invTtpk, 640,
      nullptr, 0, nullptr, 0,
      nullptr, nullptr, 256, nullptr, nullptr, nullptr, MEpk);

  // ---- one consolidated input prep (LDS transpose + fused Nyquist) ----
  input_prep<<<BN / 16 + 4 * (BN / 16), blk, 0, stream>>>(
      x, XSpk, st1, h1pk, h2pk, st2, h3pk, h4pk, RI, magpk);

  // ---- rfft (+fused magphase) ----
  mfma_gemm<M_RFFT><<<dim3(256,4), blk, 0, stream>>>(XSpk, BN, 16, fwdTpk, 512,
      nullptr, 0, nullptr, 0,
      nullptr, RI, 514, nullptr, nullptr, nullptr, magpk);

  // ---- sep block 1 (fused LSTM epilogues; c read from st directly) ----
  mfma_gemm<M_LSTM><<<dim3(256,4), blk, 0, stream>>>(magpk, BN, 9, w11pk, 512,
      h1pk, 4, wh1pk, 512,
      bg1, nullptr, 0, st1, nullptr, out_st1, h1npk);
  mfma_gemm<M_LSTM><<<dim3(256,4), blk, 0, stream>>>(h1npk, BN, 4, w12pk, 512,
      h2pk, 4, wh2pk, 512,
      bg2, nullptr, 0, st1 + (size_t)BN*NH*2, nullptr,
      out_st1 + (size_t)BN*NH*2, h2npk);
  // ---- mask1 + fused est_build -> XS packed ----
  mfma_gemm<M_EST><<<dim3(256,3), blk, 0, stream>>>(h2npk, BN, 4, dw1pk, 384,
      nullptr, 0, nullptr, 0,
      bm1, nullptr, 0, RI, magpk, nullptr, XSpk);

  // ---- encoder (irfft folded via ME) + LN ----
  mfma_gemm<M_F32><<<dim3(256,2), blk, 0, stream>>>(XSpk, BN, 17, MEpk, 256,
      nullptr, 0, nullptr, 0,
      nullptr, ENC, 256, nullptr, nullptr, nullptr, nullptr);
  ln_kernel<<<BN, 64, 0, stream>>>(ENC, ln_g, ln_b, ENCNpk);

  // ---- sep block 2 ----
  mfma_gemm<M_LSTM><<<dim3(256,4), blk, 0, stream>>>(ENCNpk, BN, 8, w21pk, 512,
      h3pk, 4, wh3pk, 512,
      bg3, nullptr, 0, st2, nullptr, out_st2, h1npk);
  mfma_gemm<M_LSTM><<<dim3(256,4), blk, 0, stream>>>(h1npk, BN, 4, w22pk, 512,
      h4pk, 4, wh4pk, 512,
      bg4, nullptr, 0, st2 + (size_t)BN*NH*2, nullptr,
      out_st2 + (size_t)BN*NH*2, h2npk);
  // ---- mask2 + fused dec_in -> D packed ----
  mfma_gemm<M_DEC><<<dim3(256,2), blk, 0, stream>>>(h2npk, BN, 4, dw2pk, 256,
      nullptr, 0, nullptr, 0,
      bm2, nullptr, 0, ENC, nullptr, nullptr, Dpk);

  // ---- decoder ----
  mfma_gemm<M_F32><<<dim3(256,4), blk, 0, stream>>>(Dpk, BN, 8, decwpk, 512,
      nullptr, 0, nullptr, 0,
      nullptr, out_dec, 512, nullptr, nullptr, nullptr, nullptr);
}